// Round 9
// baseline (280.182 us; speedup 1.0000x reference)
//
#include <hip/hip_runtime.h>
#include <math.h>

#define Bx 8
#define IMG 128
#define DD 128
#define HEADS 4
#define LL 2
#define PCc 8
#define PFf 4
#define HCc 16
#define NCc 256
#define HFf 32
#define NFf 1024
#define NTOK 1280
#define HD 32
#define SPLIT 4          // key-split factor for flash-decode attention
#define NQT 20           // NTOK/64 query tiles

typedef __attribute__((ext_vector_type(8))) short short8;
typedef __attribute__((ext_vector_type(4))) float f32x4;

__device__ __forceinline__ short f2bf(float f) {
  unsigned u = __builtin_bit_cast(unsigned, f);
  u += 0x7FFF + ((u >> 16) & 1);   // RNE
  return (short)(u >> 16);
}
__device__ __forceinline__ float bf2f(short s) {
  unsigned u = ((unsigned)(unsigned short)s) << 16;
  return __builtin_bit_cast(float, u);
}

// ---------------- batched prologue: [0,1024) prep_w, [1024,1536) sobel,
// [1536,2560) coarse patch embed (2 tokens/block)
__global__ __launch_bounds__(256) void k_prologue(const float* __restrict__ x,
    const float* __restrict__ Wpc, const float* __restrict__ bpc,
    const float* __restrict__ te,
    const float* __restrict__ Wqkv, const float* __restrict__ Wo,
    const float* __restrict__ W1, const float* __restrict__ W2,
    short* __restrict__ WtQKV, short* __restrict__ WtO,
    short* __restrict__ Wt1, short* __restrict__ Wt2,
    float* __restrict__ e, float* __restrict__ tokens) {
  int blk = blockIdx.x;
  int t = threadIdx.x;
  if (blk < 1024) {
    // ---- weight prep: transpose + bf16
    int idx = blk * 256 + t;   // 0 .. 262143
    int l = idx / 131072, r = idx % 131072;
    const float* src; short* dst; int N, off;
    if (r < 49152)      { src = Wqkv + l * 49152; dst = WtQKV + l * 49152; N = 384; off = r; }
    else if (r < 65536) { src = Wo + l * 16384;  dst = WtO + l * 16384;  N = 128; off = r - 49152; }
    else if (r < 98304) { src = W1 + l * 32768;  dst = Wt1 + l * 32768;  N = 256; off = r - 65536; }
    else                { src = W2 + l * 32768;  dst = Wt2 + l * 32768;  N = 128; off = r - 98304; }
    int k = off / N, n = off % N;
    int K = (r >= 98304) ? 256 : 128;
    dst[(size_t)n * K + k] = f2bf(src[off]);
  } else if (blk < 1536) {
    // ---- sobel + 4x4 avgpool -> cell energy
    int bt = blk - 1024;
    int b = bt >> 6, tile = bt & 63;
    int ty = tile >> 3, tx = tile & 7;
    int ly = t >> 4, lx = t & 15;
    int py = ty * 16 + ly, px = tx * 16 + lx;
    const float* img = x + (size_t)b * IMG * IMG;
    float v[3][3];
    #pragma unroll
    for (int ky = 0; ky < 3; ++ky)
      #pragma unroll
      for (int kx = 0; kx < 3; ++kx) {
        int yy = py + ky - 1, xx = px + kx - 1;
        v[ky][kx] = (yy >= 0 && yy < IMG && xx >= 0 && xx < IMG)
                        ? img[yy * IMG + xx] : 0.f;
      }
    float gx = -v[0][0] + v[0][2] - 2.f * v[1][0] + 2.f * v[1][2] - v[2][0] + v[2][2];
    float gy = -v[0][0] - 2.f * v[0][1] - v[0][2] + v[2][0] + 2.f * v[2][1] + v[2][2];
    __shared__ float sm[256];
    sm[t] = sqrtf(gx * gx + gy * gy);
    __syncthreads();
    if (t < 16) {
      int cy = t >> 2, cx = t & 3;
      float s = 0.f;
      #pragma unroll
      for (int dy = 0; dy < 4; ++dy)
        #pragma unroll
        for (int dx = 0; dx < 4; ++dx) s += sm[(cy * 4 + dy) * 16 + cx * 4 + dx];
      e[b * NFf + (ty * 4 + cy) * 32 + tx * 4 + cx] = s * (1.f / 16.f);
    }
  } else {
    // ---- coarse patch embed, 2 tokens per block
    int bt = (blk - 1536) * 2 + (t >> 7);    // b*NC + tok
    int b = bt / NCc, tok = bt % NCc;
    int hc = tok / HCc, wc = tok % HCc;
    int half = t >> 7, d = t & 127;
    __shared__ float patch[2][PCc * PCc];
    if (d < PCc * PCc) {
      int pi = d / PCc, pj = d % PCc;
      patch[half][d] = x[(b * IMG + hc * PCc + pi) * IMG + wc * PCc + pj];
    }
    __syncthreads();
    float acc = bpc[d] + te[d];
    #pragma unroll 8
    for (int i = 0; i < PCc * PCc; ++i) acc += patch[half][i] * Wpc[i * DD + d];
    tokens[(size_t)(b * NTOK + tok) * DD + d] = acc;
  }
}

// ---------------- mask at per-image mean -> stable-sort order via ballot scan
__global__ __launch_bounds__(1024) void k_edge_sort(const float* __restrict__ e,
    int* __restrict__ order, int* __restrict__ inv, float* __restrict__ msort) {
  int b = blockIdx.x;
  int t = threadIdx.x;
  int lane = t & 63, wave = t >> 6;
  float ev = e[b * NFf + t];
  __shared__ float wsum[16];
  __shared__ int wcnt[16];
  float r = ev;
  #pragma unroll
  for (int o = 32; o > 0; o >>= 1) r += __shfl_xor(r, o, 64);
  if (lane == 0) wsum[wave] = r;
  __syncthreads();
  float tot = 0.f;
  #pragma unroll
  for (int i = 0; i < 16; ++i) tot += wsum[i];
  float mean = tot * (1.f / 1024.f);
  int m = (ev > mean) ? 1 : 0;
  unsigned long long bal = __ballot(m);
  if (lane == 0) wcnt[wave] = __popcll(bal);
  __syncthreads();
  int wbase = 0, total = 0;
  #pragma unroll
  for (int i = 0; i < 16; ++i) {
    int c = wcnt[i];
    if (i < wave) wbase += c;
    total += c;
  }
  unsigned long long below = (lane == 63) ? ~0ULL : ((1ULL << (lane + 1)) - 1);
  int incl = __popcll(bal & below);
  int eb = wbase + incl - m;       // edges strictly before t
  int pos = m ? eb : (total + t - eb);
  order[b * NFf + pos] = t;
  inv[b * NFf + t] = pos;
  msort[b * NFf + pos] = (float)m;
}

// ---------------- fine patch embed + direct scatter into tokens[:, 256:]
__global__ __launch_bounds__(128) void k_fine(const float* __restrict__ x,
    const float* __restrict__ Wpf, const float* __restrict__ bpf,
    const float* __restrict__ te, const int* __restrict__ inv,
    const float* __restrict__ msort, float* __restrict__ tokens) {
  int blk = blockIdx.x;            // b*NF + t
  int b = blk / NFf, t = blk % NFf;
  int hf = t / HFf, wf = t % HFf;
  int d = threadIdx.x;
  __shared__ float patch[PFf * PFf];
  if (d < PFf * PFf) {
    int pi = d / PFf, pj = d % PFf;
    patch[d] = x[(b * IMG + hf * PFf + pi) * IMG + wf * PFf + pj];
  }
  __syncthreads();
  float acc = bpf[d];
  #pragma unroll
  for (int i = 0; i < PFf * PFf; ++i) acc += patch[i] * Wpf[i * DD + d];
  int pos = inv[b * NFf + t];
  float mk = msort[b * NFf + pos];
  tokens[(size_t)(b * NTOK + NCc + pos) * DD + d] = acc * mk + te[DD + d];
}

// ---------------- MFMA GEMM, XOR-swizzled LDS; optional fused LayerNorm on A.
// lng!=null: Av fp32 [M,128], LN applied in A-staging (K==128), B via DMA.
// lng==null: Av bf16 [M,K], both tiles via DMA.
__global__ __launch_bounds__(256) void k_gemm_mfma(const void* __restrict__ Av,
    const short* __restrict__ Wt, const float* __restrict__ bias,
    const float* __restrict__ lng, const float* __restrict__ lnb,
    float* __restrict__ Cf, short* __restrict__ Cb, int K, int N, int do_gelu) {
  __shared__ short Alds[64 * 128];
  __shared__ short Blds[64 * 128];
  int row0 = blockIdx.x * 64, col0 = blockIdx.y * 64;
  int t = threadIdx.x;
  int lane = t & 63, w = t >> 6;
  int m = lane & 15, quad = lane >> 4;
  int lrow = lane >> 4, jphys = lane & 15;   // staging sub-addressing
  f32x4 zero = {0.f, 0.f, 0.f, 0.f};
  f32x4 acc[4] = {zero, zero, zero, zero};

  for (int kb = 0; kb < K; kb += 128) {
    __syncthreads();
    if (lng) {
      // B DMA first so it overlaps the LN VALU work below
      #pragma unroll
      for (int j = 0; j < 4; ++j) {
        int c = j * 4 + w;
        int r = c * 4 + lrow;
        int jlog = jphys ^ (r & 15);
        __builtin_amdgcn_global_load_lds(
            (const unsigned*)&Wt[(size_t)(col0 + r) * 128 + jlog * 8],
            (unsigned*)&Blds[c * 512], 16, 0, 0);
      }
      // fp32 A + fused LayerNorm (K == 128, single chunk); swizzled LDS write
      int r = t >> 2, seg = t & 3;           // 4 threads/row, 32 floats each
      const float* arow = (const float*)Av + (size_t)(row0 + r) * 128 + seg * 32;
      float vv[32];
      float s = 0.f, q = 0.f;
      #pragma unroll
      for (int j = 0; j < 8; ++j) {
        float4 u = ((const float4*)arow)[j];
        vv[j * 4 + 0] = u.x; vv[j * 4 + 1] = u.y;
        vv[j * 4 + 2] = u.z; vv[j * 4 + 3] = u.w;
        s += u.x + u.y + u.z + u.w;
        q += u.x * u.x + u.y * u.y + u.z * u.z + u.w * u.w;
      }
      s += __shfl_xor(s, 1); s += __shfl_xor(s, 2);
      q += __shfl_xor(q, 1); q += __shfl_xor(q, 2);
      float mean = s * (1.f / 128.f);
      float var = q * (1.f / 128.f) - mean * mean;
      float rstd = rsqrtf(var + 1e-5f);
      #pragma unroll
      for (int j8 = 0; j8 < 4; ++j8) {
        float4 g1 = ((const float4*)(lng + seg * 32))[j8 * 2];
        float4 g2 = ((const float4*)(lng + seg * 32))[j8 * 2 + 1];
        float4 b1 = ((const float4*)(lnb + seg * 32))[j8 * 2];
        float4 b2 = ((const float4*)(lnb + seg * 32))[j8 * 2 + 1];
        short8 o;
        o[0] = f2bf((vv[j8 * 8 + 0] - mean) * rstd * g1.x + b1.x);
        o[1] = f2bf((vv[j8 * 8 + 1] - mean) * rstd * g1.y + b1.y);
        o[2] = f2bf((vv[j8 * 8 + 2] - mean) * rstd * g1.z + b1.z);
        o[3] = f2bf((vv[j8 * 8 + 3] - mean) * rstd * g1.w + b1.w);
        o[4] = f2bf((vv[j8 * 8 + 4] - mean) * rstd * g2.x + b2.x);
        o[5] = f2bf((vv[j8 * 8 + 5] - mean) * rstd * g2.y + b2.y);
        o[6] = f2bf((vv[j8 * 8 + 6] - mean) * rstd * g2.z + b2.z);
        o[7] = f2bf((vv[j8 * 8 + 7] - mean) * rstd * g2.w + b2.w);
        int jlog = seg * 4 + j8;
        int jphy = jlog ^ (r & 15);
        *(short8*)&Alds[r * 128 + jphy * 8] = o;
      }
    } else {
      const short* A = (const short*)Av;
      #pragma unroll
      for (int j = 0; j < 4; ++j) {
        int c = j * 4 + w;               // chunk-group 0..15, wave-uniform
        int r = c * 4 + lrow;            // tile row this lane fetches
        int jlog = jphys ^ (r & 15);     // XOR swizzle
        __builtin_amdgcn_global_load_lds(
            (const unsigned*)&A[(size_t)(row0 + r) * K + kb + jlog * 8],
            (unsigned*)&Alds[c * 512], 16, 0, 0);
        __builtin_amdgcn_global_load_lds(
            (const unsigned*)&Wt[(size_t)(col0 + r) * K + kb + jlog * 8],
            (unsigned*)&Blds[c * 512], 16, 0, 0);
      }
    }
    __syncthreads();
    #pragma unroll
    for (int ks = 0; ks < 4; ++ks) {   // logical chunk = quad + ks*4
      int pc = ((quad + ks * 4) ^ m) * 8;
      short8 af = *(const short8*)&Alds[(w * 16 + m) * 128 + pc];
      #pragma unroll
      for (int nt = 0; nt < 4; ++nt) {
        short8 bf = *(const short8*)&Blds[(nt * 16 + m) * 128 + pc];
        acc[nt] = __builtin_amdgcn_mfma_f32_16x16x32_bf16(af, bf, acc[nt], 0, 0, 0);
      }
    }
  }
  #pragma unroll
  for (int nt = 0; nt < 4; ++nt) {
    int col = col0 + nt * 16 + m;
    float bv = bias ? bias[col] : 0.f;
    #pragma unroll
    for (int r = 0; r < 4; ++r) {
      int row = row0 + w * 16 + quad * 4 + r;
      float v = acc[nt][r] + bv;
      if (do_gelu) v = 0.5f * v * (1.f + erff(v * 0.70710678118654752f));
      if (Cf) Cf[(size_t)row * N + col] += v;
      else    Cb[(size_t)row * N + col] = f2bf(v);
    }
  }
}

// ---------------- Wo GEMM with fused split-K combine
__global__ __launch_bounds__(256) void k_gemm_wo(const short* __restrict__ Opart,
    const float* __restrict__ Lpart, const short* __restrict__ Wt,
    const float* __restrict__ bias, float* __restrict__ Cf) {
  __shared__ short Alds[64 * 136];
  __shared__ short Blds[64 * 128];
  int row0 = blockIdx.x * 64, col0 = blockIdx.y * 64;
  int b = row0 / NTOK, qt = (row0 / 64) % NQT;
  int t = threadIdx.x;
  int lane = t & 63, w = t >> 6;
  int m = lane & 15, quad = lane >> 4;
  int lrow = lane >> 4, jphys = lane & 15;
  f32x4 zero = {0.f, 0.f, 0.f, 0.f};
  f32x4 acc[4] = {zero, zero, zero, zero};

  // ---- B staging first (DMA overlaps the A combine VALU work)
  #pragma unroll
  for (int j = 0; j < 4; ++j) {
    int c = j * 4 + w;
    int r = c * 4 + lrow;
    int jlog = jphys ^ (r & 15);
    __builtin_amdgcn_global_load_lds(
        (const unsigned*)&Wt[(size_t)(col0 + r) * 128 + jlog * 8],
        (unsigned*)&Blds[c * 512], 16, 0, 0);
  }
  // ---- A staging: combine 4 split-K partials, normalize by L, write bf16
  #pragma unroll
  for (int it = 0; it < 4; ++it) {
    int idx = t + it * 256;            // 1024 short8 chunks
    int q = idx >> 4, j = idx & 15;
    int hh = j >> 2, dd = (j & 3) * 8;
    size_t pb = ((size_t)(b * HEADS + hh) * NQT + qt) * SPLIT;
    float L = Lpart[(pb + 0) * 64 + q] + Lpart[(pb + 1) * 64 + q]
            + Lpart[(pb + 2) * 64 + q] + Lpart[(pb + 3) * 64 + q];
    float o[8] = {0, 0, 0, 0, 0, 0, 0, 0};
    #pragma unroll
    for (int sk = 0; sk < SPLIT; ++sk) {
      short8 po = *(const short8*)&Opart[(pb + sk) * 2048 + q * 32 + dd];
      #pragma unroll
      for (int i = 0; i < 8; ++i) o[i] += bf2f(po[i]);
    }
    float rs = 1.f / L;
    short8 ov;
    #pragma unroll
    for (int i = 0; i < 8; ++i) ov[i] = f2bf(o[i] * rs);
    *(short8*)&Alds[q * 136 + j * 8] = ov;
  }
  __syncthreads();
  #pragma unroll
  for (int ks = 0; ks < 4; ++ks) {
    short8 af = *(const short8*)&Alds[(w * 16 + m) * 136 + quad * 8 + ks * 32];
    int pc = ((quad + ks * 4) ^ m) * 8;
    #pragma unroll
    for (int nt = 0; nt < 4; ++nt) {
      short8 bf = *(const short8*)&Blds[(nt * 16 + m) * 128 + pc];
      acc[nt] = __builtin_amdgcn_mfma_f32_16x16x32_bf16(af, bf, acc[nt], 0, 0, 0);
    }
  }
  #pragma unroll
  for (int nt = 0; nt < 4; ++nt) {
    int col = col0 + nt * 16 + m;
    float bv = bias[col];
    #pragma unroll
    for (int r = 0; r < 4; ++r) {
      int row = row0 + w * 16 + quad * 4 + r;
      Cf[(size_t)row * DD + col] += acc[nt][r] + bv;
    }
  }
}

// ---------------- flash attention (R7 config): split-K, fixed-max softmax,
// swizzled Ks, two barriers/stage (implicit wave overlap does the pipelining)
__global__ __launch_bounds__(256) void k_attn4(const short* __restrict__ qkv,
    short* __restrict__ Opart, float* __restrict__ Lpart) {
  __shared__ short Ks[64 * 32];      // [key][d], DMA, chunk swizzle f(k)=(k>>1)&3
  __shared__ short Vt[32 * 74];      // [d][key], stride 74 (free scatter+gather)
  __shared__ short Pl[4][16 * 74];   // per-wave P [q][key]

  int sk = blockIdx.x % SPLIT;
  int qt = (blockIdx.x / SPLIT) % NQT;
  int h  = (blockIdx.x / (SPLIT * NQT)) % HEADS;
  int b  = blockIdx.x / (SPLIT * NQT * HEADS);
  int t = threadIdx.x;
  int lane = t & 63, w = t >> 6;
  int m = lane & 15, quad = lane >> 4;
  int q0 = qt * 64 + w * 16;

  const float scale = 0.17677669529663687f;  // 1/sqrt(32), folded into Q
  short8 qraw = *(const short8*)(qkv + ((size_t)(b * NTOK) + q0 + m) * 384 + h * HD + quad * 8);
  short8 qf;
  #pragma unroll
  for (int j = 0; j < 8; ++j) qf[j] = f2bf(bf2f(qraw[j]) * scale);

  f32x4 zero = {0.f, 0.f, 0.f, 0.f};
  f32x4 Oacc[2] = {zero, zero};
  float psum[4] = {0.f, 0.f, 0.f, 0.f};

  int skey = t >> 2, sdseg = t & 3;  // staging: key 0..63, 8 dims each
  int jlogK = sdseg ^ ((skey >> 1) & 3);
  const short* kstage = qkv + ((size_t)(b * NTOK) + skey) * 384 + 128 + h * HD + jlogK * 8;
  const short* vstage = qkv + ((size_t)(b * NTOK) + skey) * 384 + 256 + h * HD + sdseg * 8;
  int kswz = (quad ^ ((m >> 1) & 3)) * 8;   // read-side physical chunk offset

  for (int s = sk * 5; s < sk * 5 + 5; ++s) {
    __syncthreads();
    __builtin_amdgcn_global_load_lds((const unsigned*)(kstage + (size_t)s * 64 * 384),
                                     (unsigned*)&Ks[w * 512], 16, 0, 0);
    short8 vf = *(const short8*)(vstage + (size_t)s * 64 * 384);
    #pragma unroll
    for (int j = 0; j < 8; ++j) Vt[(sdseg * 8 + j) * 74 + skey] = vf[j];
    __syncthreads();

    // S = Q K^T (C-layout: row=4*quad+reg, col=m); Q pre-scaled
    f32x4 sc[4];
    #pragma unroll
    for (int ct = 0; ct < 4; ++ct) {
      short8 kfrag = *(const short8*)&Ks[(ct * 16 + m) * 32 + kswz];
      sc[ct] = __builtin_amdgcn_mfma_f32_16x16x32_bf16(qf, kfrag, zero, 0, 0, 0);
    }
    // fixed-max softmax: p = exp(s); l accumulated from TRUNCATED p (bias-free)
    #pragma unroll
    for (int ct = 0; ct < 4; ++ct)
      #pragma unroll
      for (int r = 0; r < 4; ++r) {
        float p = __expf(sc[ct][r]);
        unsigned u = __builtin_bit_cast(unsigned, p);
        psum[r] += __builtin_bit_cast(float, u & 0xffff0000u);
        Pl[w][(quad * 4 + r) * 74 + ct * 16 + m] = (short)(u >> 16);
      }
    // O += P @ V
    #pragma unroll
    for (int ks = 0; ks < 2; ++ks) {
      short8 pfrag = *(const short8*)&Pl[w][m * 74 + ks * 32 + quad * 8];
      #pragma unroll
      for (int nt = 0; nt < 2; ++nt) {
        short8 vfrag = *(const short8*)&Vt[(nt * 16 + m) * 74 + ks * 32 + quad * 8];
        Oacc[nt] = __builtin_amdgcn_mfma_f32_16x16x32_bf16(pfrag, vfrag, Oacc[nt], 0, 0, 0);
      }
    }
  }
  // single final ladder per row; write partial O (unnormalized) + l
  #pragma unroll
  for (int r = 0; r < 4; ++r) {
    float ssum = psum[r];
    #pragma unroll
    for (int o = 1; o < 16; o <<= 1) ssum += __shfl_xor(ssum, o);
    int qloc = w * 16 + quad * 4 + r;
    #pragma unroll
    for (int nt = 0; nt < 2; ++nt)
      Opart[(size_t)blockIdx.x * 2048 + qloc * 32 + nt * 16 + m] = f2bf(Oacc[nt][r]);
    if (m == 0) Lpart[(size_t)blockIdx.x * 64 + qloc] = ssum;
  }
}

// ---------------- fused decoder: coarse head + bilinear, fine head + scatter,
// conv3x3+relu+conv3x3 — one block per image, everything in LDS
__global__ __launch_bounds__(1024) void k_decoder(const float* __restrict__ tokens,
    const float* __restrict__ dWc, const float* __restrict__ dbc,
    const float* __restrict__ dWf, const float* __restrict__ dbf,
    const float* __restrict__ msort, const int* __restrict__ order,
    const float* __restrict__ fW1, const float* __restrict__ fb1,
    const float* __restrict__ fW2, const float* __restrict__ fb2,
    float* __restrict__ outp) {
  int b = blockIdx.x;
  int t = threadIdx.x;
  __shared__ float cmap[NCc];
  __shared__ float fmap[1024];
  __shared__ float cup[1024];
  __shared__ float hb[2][1024];
  // fine head: token j = t (sorted order), scatter to pixel order
  {
    const float* row = tokens + (size_t)(b * NTOK + NCc + t) * DD;
    float a = 0.f;
    #pragma unroll 8
    for (int d4 = 0; d4 < 32; ++d4) {
      float4 u = ((const float4*)row)[d4];
      float4 wv = ((const float4*)dWf)[d4];
      a += u.x * wv.x + u.y * wv.y + u.z * wv.z + u.w * wv.w;
    }
    a = (a + dbf[0]) * msort[b * NFf + t];
    fmap[order[b * NFf + t]] = a;   // 32->32 AC-bilinear is identity
  }
  if (t < NCc) {
    const float* row = tokens + (size_t)(b * NTOK + t) * DD;
    float a = 0.f;
    #pragma unroll 8
    for (int d4 = 0; d4 < 32; ++d4) {
      float4 u = ((const float4*)row)[d4];
      float4 wv = ((const float4*)dWc)[d4];
      a += u.x * wv.x + u.y * wv.y + u.z * wv.z + u.w * wv.w;
    }
    cmap[t] = a + dbc[0];
  }
  __syncthreads();
  // coarse 16->32 align-corners bilinear
  int y = t >> 5, x = t & 31;
  {
    float ys = y * (15.f / 31.f);
    float xs = x * (15.f / 31.f);
    int y0 = (int)floorf(ys); int y1 = min(y0 + 1, 15); float wy = ys - (float)y0;
    int x0 = (int)floorf(xs); int x1 = min(x0 + 1, 15); float wx = xs - (float)x0;
    cup[t] = cmap[y0 * 16 + x0] * (1.f - wy) * (1.f - wx)
           + cmap[y0 * 16 + x1] * (1.f - wy) * wx
           + cmap[y1 * 16 + x0] * wy * (1.f - wx)
           + cmap[y1 * 16 + x1] * wy * wx;
  }
  __syncthreads();
  // conv1 + relu
  for (int oc = 0; oc < 2; ++oc) {
    float a = fb1[oc];
    #pragma unroll
    for (int ic = 0; ic < 2; ++ic)
      #pragma unroll
      for (int ky = 0; ky < 3; ++ky)
        #pragma unroll
        for (int kx = 0; kx < 3; ++kx) {
          int yy = y + ky - 1, xx = x + kx - 1;
          float v = 0.f;
          if (yy >= 0 && yy < 32 && xx >= 0 && xx < 32)
            v = ic == 0 ? cup[yy * 32 + xx] : fmap[yy * 32 + xx];
          a += v * fW1[((oc * 2 + ic) * 3 + ky) * 3 + kx];
        }
    hb[oc][t] = fmaxf(a, 0.f);
  }
  __syncthreads();
  // conv2 -> out
  float a = fb2[0];
  #pragma unroll
  for (int ic = 0; ic < 2; ++ic)
    #pragma unroll
    for (int ky = 0; ky < 3; ++ky)
      #pragma unroll
      for (int kx = 0; kx < 3; ++kx) {
        int yy = y + ky - 1, xx = x + kx - 1;
        float v = (yy >= 0 && yy < 32 && xx >= 0 && xx < 32)
                      ? hb[ic][yy * 32 + xx] : 0.f;
        a += v * fW2[(ic * 3 + ky) * 3 + kx];
      }
  outp[b * 1024 + t] = a;
}

extern "C" void kernel_launch(void* const* d_in, const int* in_sizes, int n_in,
                              void* d_out, int out_size, void* d_ws, size_t ws_size,
                              hipStream_t stream) {
  const float* x    = (const float*)d_in[0];
  const float* Wpc  = (const float*)d_in[1];
  const float* bpc  = (const float*)d_in[2];
  const float* Wpf  = (const float*)d_in[3];
  const float* bpf  = (const float*)d_in[4];
  const float* te   = (const float*)d_in[5];
  const float* ln1g = (const float*)d_in[6];
  const float* ln1b = (const float*)d_in[7];
  const float* Wqkv = (const float*)d_in[8];
  const float* Wo   = (const float*)d_in[9];
  const float* bo   = (const float*)d_in[10];
  const float* ln2g = (const float*)d_in[11];
  const float* ln2b = (const float*)d_in[12];
  const float* W1   = (const float*)d_in[13];
  const float* b1   = (const float*)d_in[14];
  const float* W2   = (const float*)d_in[15];
  const float* b2   = (const float*)d_in[16];
  const float* dWc  = (const float*)d_in[17];
  const float* dbc  = (const float*)d_in[18];
  const float* dWf  = (const float*)d_in[19];
  const float* dbf  = (const float*)d_in[20];
  const float* fW1  = (const float*)d_in[21];
  const float* fb1  = (const float*)d_in[22];
  const float* fW2  = (const float*)d_in[23];
  const float* fb2  = (const float*)d_in[24];

  char* ws = (char*)d_ws;
  float* tokens = (float*)ws;                 ws += 1310720 * 4;   // fp32 [B*N,128]
  short* qkvb   = (short*)ws;                 ws += 3932160 * 2;   // bf16 [B*N,384]
  short* hbuf   = (short*)ws;                 ws += 2621440 * 2;   // bf16 [B*N,256]
  short* Opart  = (short*)ws;                 ws += (size_t)(Bx * HEADS * NQT * SPLIT) * 2048 * 2;
  float* Lpart  = (float*)ws;                 ws += (size_t)(Bx * HEADS * NQT * SPLIT) * 64 * 4;
  short* WtQKV  = (short*)ws;                 ws += 98304 * 2;     // [L][384][128]
  short* WtO    = (short*)ws;                 ws += 32768 * 2;     // [L][128][128]
  short* Wt1    = (short*)ws;                 ws += 65536 * 2;     // [L][256][128]
  short* Wt2    = (short*)ws;                 ws += 65536 * 2;     // [L][128][256]
  float* ebuf   = (float*)ws;                 ws += 8192 * 4;
  float* msort  = (float*)ws;                 ws += 8192 * 4;
  int*   order  = (int*)ws;                   ws += 8192 * 4;
  int*   inv    = (int*)ws;                   ws += 8192 * 4;

  const int M = Bx * NTOK;                    // 10240

  k_prologue<<<2560, 256, 0, stream>>>(x, Wpc, bpc, te, Wqkv, Wo, W1, W2,
                                       WtQKV, WtO, Wt1, Wt2, ebuf, tokens);
  k_edge_sort<<<Bx, 1024, 0, stream>>>(ebuf, order, inv, msort);
  k_fine<<<Bx * NFf, 128, 0, stream>>>(x, Wpf, bpf, te, inv, msort, tokens);

  for (int l = 0; l < LL; ++l) {
    k_gemm_mfma<<<dim3(M / 64, 384 / 64), 256, 0, stream>>>(
        tokens, WtQKV + (size_t)l * 49152, nullptr,
        ln1g + l * DD, ln1b + l * DD, nullptr, qkvb, 128, 384, 0);
    k_attn4<<<Bx * HEADS * NQT * SPLIT, 256, 0, stream>>>(qkvb, Opart, Lpart);
    k_gemm_wo<<<dim3(M / 64, 2), 256, 0, stream>>>(
        Opart, Lpart, WtO + (size_t)l * 16384, bo + l * DD, tokens);
    k_gemm_mfma<<<dim3(M / 64, 256 / 64), 256, 0, stream>>>(
        tokens, Wt1 + (size_t)l * 32768, b1 + l * 256,
        ln2g + l * DD, ln2b + l * DD, nullptr, hbuf, 128, 256, 1);
    k_gemm_mfma<<<dim3(M / 64, 128 / 64), 256, 0, stream>>>(
        hbuf, Wt2 + (size_t)l * 32768, b2 + l * DD,
        nullptr, nullptr, tokens, nullptr, 256, 128, 0);
  }

  k_decoder<<<Bx, 1024, 0, stream>>>(tokens, dWc, dbc, dWf, dbf, msort, order,
                                     fW1, fb1, fW2, fb2, (float*)d_out);
}

// Round 11
// 262.344 us; speedup vs baseline: 1.0680x; 1.0680x over previous
//
#include <hip/hip_runtime.h>
#include <math.h>

#define Bx 8
#define IMG 128
#define DD 128
#define HEADS 4
#define LL 2
#define PCc 8
#define PFf 4
#define HCc 16
#define NCc 256
#define HFf 32
#define NFf 1024
#define NTOK 1280
#define HD 32
#define SPLIT 4          // key-split factor for flash-decode attention
#define NQT 20           // NTOK/64 query tiles

typedef __attribute__((ext_vector_type(8))) short short8;
typedef __attribute__((ext_vector_type(4))) float f32x4;

__device__ __forceinline__ short f2bf(float f) {
  unsigned u = __builtin_bit_cast(unsigned, f);
  u += 0x7FFF + ((u >> 16) & 1);   // RNE
  return (short)(u >> 16);
}
__device__ __forceinline__ float bf2f(short s) {
  unsigned u = ((unsigned)(unsigned short)s) << 16;
  return __builtin_bit_cast(float, u);
}

// ---------------- batched prologue: [0,1024) prep_w, [1024,1536) sobel,
// [1536,2560) coarse patch embed (2 tokens/block)
__global__ __launch_bounds__(256) void k_prologue(const float* __restrict__ x,
    const float* __restrict__ Wpc, const float* __restrict__ bpc,
    const float* __restrict__ te,
    const float* __restrict__ Wqkv, const float* __restrict__ Wo,
    const float* __restrict__ W1, const float* __restrict__ W2,
    short* __restrict__ WtQKV, short* __restrict__ WtO,
    short* __restrict__ Wt1, short* __restrict__ Wt2,
    float* __restrict__ e, float* __restrict__ tokens) {
  int blk = blockIdx.x;
  int t = threadIdx.x;
  if (blk < 1024) {
    // ---- weight prep: transpose + bf16
    int idx = blk * 256 + t;   // 0 .. 262143
    int l = idx / 131072, r = idx % 131072;
    const float* src; short* dst; int N, off;
    if (r < 49152)      { src = Wqkv + l * 49152; dst = WtQKV + l * 49152; N = 384; off = r; }
    else if (r < 65536) { src = Wo + l * 16384;  dst = WtO + l * 16384;  N = 128; off = r - 49152; }
    else if (r < 98304) { src = W1 + l * 32768;  dst = Wt1 + l * 32768;  N = 256; off = r - 65536; }
    else                { src = W2 + l * 32768;  dst = Wt2 + l * 32768;  N = 128; off = r - 98304; }
    int k = off / N, n = off % N;
    int K = (r >= 98304) ? 256 : 128;
    dst[(size_t)n * K + k] = f2bf(src[off]);
  } else if (blk < 1536) {
    // ---- sobel + 4x4 avgpool -> cell energy
    int bt = blk - 1024;
    int b = bt >> 6, tile = bt & 63;
    int ty = tile >> 3, tx = tile & 7;
    int ly = t >> 4, lx = t & 15;
    int py = ty * 16 + ly, px = tx * 16 + lx;
    const float* img = x + (size_t)b * IMG * IMG;
    float v[3][3];
    #pragma unroll
    for (int ky = 0; ky < 3; ++ky)
      #pragma unroll
      for (int kx = 0; kx < 3; ++kx) {
        int yy = py + ky - 1, xx = px + kx - 1;
        v[ky][kx] = (yy >= 0 && yy < IMG && xx >= 0 && xx < IMG)
                        ? img[yy * IMG + xx] : 0.f;
      }
    float gx = -v[0][0] + v[0][2] - 2.f * v[1][0] + 2.f * v[1][2] - v[2][0] + v[2][2];
    float gy = -v[0][0] - 2.f * v[0][1] - v[0][2] + v[2][0] + 2.f * v[2][1] + v[2][2];
    __shared__ float sm[256];
    sm[t] = sqrtf(gx * gx + gy * gy);
    __syncthreads();
    if (t < 16) {
      int cy = t >> 2, cx = t & 3;
      float s = 0.f;
      #pragma unroll
      for (int dy = 0; dy < 4; ++dy)
        #pragma unroll
        for (int dx = 0; dx < 4; ++dx) s += sm[(cy * 4 + dy) * 16 + cx * 4 + dx];
      e[b * NFf + (ty * 4 + cy) * 32 + tx * 4 + cx] = s * (1.f / 16.f);
    }
  } else {
    // ---- coarse patch embed, 2 tokens per block
    int bt = (blk - 1536) * 2 + (t >> 7);    // b*NC + tok
    int b = bt / NCc, tok = bt % NCc;
    int hc = tok / HCc, wc = tok % HCc;
    int half = t >> 7, d = t & 127;
    __shared__ float patch[2][PCc * PCc];
    if (d < PCc * PCc) {
      int pi = d / PCc, pj = d % PCc;
      patch[half][d] = x[(b * IMG + hc * PCc + pi) * IMG + wc * PCc + pj];
    }
    __syncthreads();
    float acc = bpc[d] + te[d];
    #pragma unroll 8
    for (int i = 0; i < PCc * PCc; ++i) acc += patch[half][i] * Wpc[i * DD + d];
    tokens[(size_t)(b * NTOK + tok) * DD + d] = acc;
  }
}

// ---------------- mask at per-image mean -> stable-sort order via ballot scan
__global__ __launch_bounds__(1024) void k_edge_sort(const float* __restrict__ e,
    int* __restrict__ order, int* __restrict__ inv, float* __restrict__ msort) {
  int b = blockIdx.x;
  int t = threadIdx.x;
  int lane = t & 63, wave = t >> 6;
  float ev = e[b * NFf + t];
  __shared__ float wsum[16];
  __shared__ int wcnt[16];
  float r = ev;
  #pragma unroll
  for (int o = 32; o > 0; o >>= 1) r += __shfl_xor(r, o, 64);
  if (lane == 0) wsum[wave] = r;
  __syncthreads();
  float tot = 0.f;
  #pragma unroll
  for (int i = 0; i < 16; ++i) tot += wsum[i];
  float mean = tot * (1.f / 1024.f);
  int m = (ev > mean) ? 1 : 0;
  unsigned long long bal = __ballot(m);
  if (lane == 0) wcnt[wave] = __popcll(bal);
  __syncthreads();
  int wbase = 0, total = 0;
  #pragma unroll
  for (int i = 0; i < 16; ++i) {
    int c = wcnt[i];
    if (i < wave) wbase += c;
    total += c;
  }
  unsigned long long below = (lane == 63) ? ~0ULL : ((1ULL << (lane + 1)) - 1);
  int incl = __popcll(bal & below);
  int eb = wbase + incl - m;       // edges strictly before t
  int pos = m ? eb : (total + t - eb);
  order[b * NFf + pos] = t;
  inv[b * NFf + t] = pos;
  msort[b * NFf + pos] = (float)m;
}

// ---------------- fine patch embed + direct scatter into tokens[:, 256:]
__global__ __launch_bounds__(128) void k_fine(const float* __restrict__ x,
    const float* __restrict__ Wpf, const float* __restrict__ bpf,
    const float* __restrict__ te, const int* __restrict__ inv,
    const float* __restrict__ msort, float* __restrict__ tokens) {
  int blk = blockIdx.x;            // b*NF + t
  int b = blk / NFf, t = blk % NFf;
  int hf = t / HFf, wf = t % HFf;
  int d = threadIdx.x;
  __shared__ float patch[PFf * PFf];
  if (d < PFf * PFf) {
    int pi = d / PFf, pj = d % PFf;
    patch[d] = x[(b * IMG + hf * PFf + pi) * IMG + wf * PFf + pj];
  }
  __syncthreads();
  float acc = bpf[d];
  #pragma unroll
  for (int i = 0; i < PFf * PFf; ++i) acc += patch[i] * Wpf[i * DD + d];
  int pos = inv[b * NFf + t];
  float mk = msort[b * NFf + pos];
  tokens[(size_t)(b * NTOK + NCc + pos) * DD + d] = acc * mk + te[DD + d];
}

// ---------------- LayerNorm over D=128, one wave per row, out bf16
// (standalone: LN-into-GEMM fusion measured -25us in R9 — rejected)
__global__ __launch_bounds__(256) void k_ln_bf16(const float* __restrict__ inp,
    const float* __restrict__ g, const float* __restrict__ bb,
    short* __restrict__ outp) {
  int row = blockIdx.x * 4 + (threadIdx.x >> 6);
  int lane = threadIdx.x & 63;
  float2 v = ((const float2*)(inp + (size_t)row * DD))[lane];
  float s = v.x + v.y;
  #pragma unroll
  for (int o = 32; o > 0; o >>= 1) s += __shfl_xor(s, o, 64);
  float mean = s * (1.f / 128.f);
  float cx = v.x - mean, cy = v.y - mean;
  float q = cx * cx + cy * cy;
  #pragma unroll
  for (int o = 32; o > 0; o >>= 1) q += __shfl_xor(q, o, 64);
  float rstd = rsqrtf(q * (1.f / 128.f) + 1e-5f);
  float2 gg = ((const float2*)g)[lane];
  float2 bv = ((const float2*)bb)[lane];
  int p = (int)(unsigned short)f2bf(cx * rstd * gg.x + bv.x)
        | ((int)(unsigned short)f2bf(cy * rstd * gg.y + bv.y) << 16);
  ((int*)(outp + (size_t)row * DD))[lane] = p;
}

// ---------------- MFMA GEMM, async DMA staging with XOR-swizzled LDS layout
__global__ __launch_bounds__(256) void k_gemm_mfma(const short* __restrict__ A,
    const short* __restrict__ Wt, const float* __restrict__ bias,
    float* __restrict__ Cf, short* __restrict__ Cb, int K, int N, int do_gelu) {
  __shared__ short Alds[64 * 128];
  __shared__ short Blds[64 * 128];
  int row0 = blockIdx.x * 64, col0 = blockIdx.y * 64;
  int t = threadIdx.x;
  int lane = t & 63, w = t >> 6;
  int m = lane & 15, quad = lane >> 4;
  int lrow = lane >> 4, jphys = lane & 15;   // staging sub-addressing
  f32x4 zero = {0.f, 0.f, 0.f, 0.f};
  f32x4 acc[4] = {zero, zero, zero, zero};

  for (int kb = 0; kb < K; kb += 128) {
    __syncthreads();
    #pragma unroll
    for (int j = 0; j < 4; ++j) {
      int c = j * 4 + w;               // chunk-group 0..15, wave-uniform
      int r = c * 4 + lrow;            // tile row this lane fetches
      int jlog = jphys ^ (r & 15);     // XOR swizzle
      __builtin_amdgcn_global_load_lds(
          (const unsigned*)&A[(size_t)(row0 + r) * K + kb + jlog * 8],
          (unsigned*)&Alds[c * 512], 16, 0, 0);
      __builtin_amdgcn_global_load_lds(
          (const unsigned*)&Wt[(size_t)(col0 + r) * K + kb + jlog * 8],
          (unsigned*)&Blds[c * 512], 16, 0, 0);
    }
    __syncthreads();
    #pragma unroll
    for (int ks = 0; ks < 4; ++ks) {   // logical chunk = quad + ks*4
      int pc = ((quad + ks * 4) ^ m) * 8;
      short8 af = *(const short8*)&Alds[(w * 16 + m) * 128 + pc];
      #pragma unroll
      for (int nt = 0; nt < 4; ++nt) {
        short8 bf = *(const short8*)&Blds[(nt * 16 + m) * 128 + pc];
        acc[nt] = __builtin_amdgcn_mfma_f32_16x16x32_bf16(af, bf, acc[nt], 0, 0, 0);
      }
    }
  }
  #pragma unroll
  for (int nt = 0; nt < 4; ++nt) {
    int col = col0 + nt * 16 + m;
    float bv = bias ? bias[col] : 0.f;
    #pragma unroll
    for (int r = 0; r < 4; ++r) {
      int row = row0 + w * 16 + quad * 4 + r;
      float v = acc[nt][r] + bv;
      if (do_gelu) v = 0.5f * v * (1.f + erff(v * 0.70710678118654752f));
      if (Cf) Cf[(size_t)row * N + col] += v;
      else    Cb[(size_t)row * N + col] = f2bf(v);
    }
  }
}

// ---------------- Wo GEMM with fused split-K combine
__global__ __launch_bounds__(256) void k_gemm_wo(const short* __restrict__ Opart,
    const float* __restrict__ Lpart, const short* __restrict__ Wt,
    const float* __restrict__ bias, float* __restrict__ Cf) {
  __shared__ short Alds[64 * 136];
  __shared__ short Blds[64 * 128];
  int row0 = blockIdx.x * 64, col0 = blockIdx.y * 64;
  int b = row0 / NTOK, qt = (row0 / 64) % NQT;
  int t = threadIdx.x;
  int lane = t & 63, w = t >> 6;
  int m = lane & 15, quad = lane >> 4;
  int lrow = lane >> 4, jphys = lane & 15;
  f32x4 zero = {0.f, 0.f, 0.f, 0.f};
  f32x4 acc[4] = {zero, zero, zero, zero};

  // ---- B staging first (DMA overlaps the A combine VALU work)
  #pragma unroll
  for (int j = 0; j < 4; ++j) {
    int c = j * 4 + w;
    int r = c * 4 + lrow;
    int jlog = jphys ^ (r & 15);
    __builtin_amdgcn_global_load_lds(
        (const unsigned*)&Wt[(size_t)(col0 + r) * 128 + jlog * 8],
        (unsigned*)&Blds[c * 512], 16, 0, 0);
  }
  // ---- A staging: combine 4 split-K partials, normalize by L, write bf16
  #pragma unroll
  for (int it = 0; it < 4; ++it) {
    int idx = t + it * 256;            // 1024 short8 chunks
    int q = idx >> 4, j = idx & 15;
    int hh = j >> 2, dd = (j & 3) * 8;
    size_t pb = ((size_t)(b * HEADS + hh) * NQT + qt) * SPLIT;
    float L = Lpart[(pb + 0) * 64 + q] + Lpart[(pb + 1) * 64 + q]
            + Lpart[(pb + 2) * 64 + q] + Lpart[(pb + 3) * 64 + q];
    float o[8] = {0, 0, 0, 0, 0, 0, 0, 0};
    #pragma unroll
    for (int sk = 0; sk < SPLIT; ++sk) {
      short8 po = *(const short8*)&Opart[(pb + sk) * 2048 + q * 32 + dd];
      #pragma unroll
      for (int i = 0; i < 8; ++i) o[i] += bf2f(po[i]);
    }
    float rs = 1.f / L;
    short8 ov;
    #pragma unroll
    for (int i = 0; i < 8; ++i) ov[i] = f2bf(o[i] * rs);
    *(short8*)&Alds[q * 136 + j * 8] = ov;
  }
  __syncthreads();
  #pragma unroll
  for (int ks = 0; ks < 4; ++ks) {
    short8 af = *(const short8*)&Alds[(w * 16 + m) * 136 + quad * 8 + ks * 32];
    int pc = ((quad + ks * 4) ^ m) * 8;
    #pragma unroll
    for (int nt = 0; nt < 4; ++nt) {
      short8 bf = *(const short8*)&Blds[(nt * 16 + m) * 128 + pc];
      acc[nt] = __builtin_amdgcn_mfma_f32_16x16x32_bf16(af, bf, acc[nt], 0, 0, 0);
    }
  }
  #pragma unroll
  for (int nt = 0; nt < 4; ++nt) {
    int col = col0 + nt * 16 + m;
    float bv = bias[col];
    #pragma unroll
    for (int r = 0; r < 4; ++r) {
      int row = row0 + w * 16 + quad * 4 + r;
      Cf[(size_t)row * DD + col] += acc[nt][r] + bv;
    }
  }
}

// ---------------- flash attention (R7 config): split-K, fixed-max softmax,
// swizzled Ks, two barriers/stage (implicit wave overlap does the pipelining)
__global__ __launch_bounds__(256) void k_attn4(const short* __restrict__ qkv,
    short* __restrict__ Opart, float* __restrict__ Lpart) {
  __shared__ short Ks[64 * 32];      // [key][d], DMA, chunk swizzle f(k)=(k>>1)&3
  __shared__ short Vt[32 * 74];      // [d][key], stride 74 (free scatter+gather)
  __shared__ short Pl[4][16 * 74];   // per-wave P [q][key]

  int sk = blockIdx.x % SPLIT;
  int qt = (blockIdx.x / SPLIT) % NQT;
  int h  = (blockIdx.x / (SPLIT * NQT)) % HEADS;
  int b  = blockIdx.x / (SPLIT * NQT * HEADS);
  int t = threadIdx.x;
  int lane = t & 63, w = t >> 6;
  int m = lane & 15, quad = lane >> 4;
  int q0 = qt * 64 + w * 16;

  const float scale = 0.17677669529663687f;  // 1/sqrt(32), folded into Q
  short8 qraw = *(const short8*)(qkv + ((size_t)(b * NTOK) + q0 + m) * 384 + h * HD + quad * 8);
  short8 qf;
  #pragma unroll
  for (int j = 0; j < 8; ++j) qf[j] = f2bf(bf2f(qraw[j]) * scale);

  f32x4 zero = {0.f, 0.f, 0.f, 0.f};
  f32x4 Oacc[2] = {zero, zero};
  float psum[4] = {0.f, 0.f, 0.f, 0.f};

  int skey = t >> 2, sdseg = t & 3;  // staging: key 0..63, 8 dims each
  int jlogK = sdseg ^ ((skey >> 1) & 3);
  const short* kstage = qkv + ((size_t)(b * NTOK) + skey) * 384 + 128 + h * HD + jlogK * 8;
  const short* vstage = qkv + ((size_t)(b * NTOK) + skey) * 384 + 256 + h * HD + sdseg * 8;
  int kswz = (quad ^ ((m >> 1) & 3)) * 8;   // read-side physical chunk offset

  for (int s = sk * 5; s < sk * 5 + 5; ++s) {
    __syncthreads();
    __builtin_amdgcn_global_load_lds((const unsigned*)(kstage + (size_t)s * 64 * 384),
                                     (unsigned*)&Ks[w * 512], 16, 0, 0);
    short8 vf = *(const short8*)(vstage + (size_t)s * 64 * 384);
    #pragma unroll
    for (int j = 0; j < 8; ++j) Vt[(sdseg * 8 + j) * 74 + skey] = vf[j];
    __syncthreads();

    // S = Q K^T (C-layout: row=4*quad+reg, col=m); Q pre-scaled
    f32x4 sc[4];
    #pragma unroll
    for (int ct = 0; ct < 4; ++ct) {
      short8 kfrag = *(const short8*)&Ks[(ct * 16 + m) * 32 + kswz];
      sc[ct] = __builtin_amdgcn_mfma_f32_16x16x32_bf16(qf, kfrag, zero, 0, 0, 0);
    }
    // fixed-max softmax: p = exp(s); l accumulated from TRUNCATED p (bias-free)
    #pragma unroll
    for (int ct = 0; ct < 4; ++ct)
      #pragma unroll
      for (int r = 0; r < 4; ++r) {
        float p = __expf(sc[ct][r]);
        unsigned u = __builtin_bit_cast(unsigned, p);
        psum[r] += __builtin_bit_cast(float, u & 0xffff0000u);
        Pl[w][(quad * 4 + r) * 74 + ct * 16 + m] = (short)(u >> 16);
      }
    // O += P @ V
    #pragma unroll
    for (int ks = 0; ks < 2; ++ks) {
      short8 pfrag = *(const short8*)&Pl[w][m * 74 + ks * 32 + quad * 8];
      #pragma unroll
      for (int nt = 0; nt < 2; ++nt) {
        short8 vfrag = *(const short8*)&Vt[(nt * 16 + m) * 74 + ks * 32 + quad * 8];
        Oacc[nt] = __builtin_amdgcn_mfma_f32_16x16x32_bf16(pfrag, vfrag, Oacc[nt], 0, 0, 0);
      }
    }
  }
  // single final ladder per row; write partial O (unnormalized) + l
  #pragma unroll
  for (int r = 0; r < 4; ++r) {
    float ssum = psum[r];
    #pragma unroll
    for (int o = 1; o < 16; o <<= 1) ssum += __shfl_xor(ssum, o);
    int qloc = w * 16 + quad * 4 + r;
    #pragma unroll
    for (int nt = 0; nt < 2; ++nt)
      Opart[(size_t)blockIdx.x * 2048 + qloc * 32 + nt * 16 + m] = f2bf(Oacc[nt][r]);
    if (m == 0) Lpart[(size_t)blockIdx.x * 64 + qloc] = ssum;
  }
}

// ---------------- fused decoder: coarse head + bilinear, fine head + scatter,
// conv3x3+relu+conv3x3 — one block per image, everything in LDS
__global__ __launch_bounds__(1024) void k_decoder(const float* __restrict__ tokens,
    const float* __restrict__ dWc, const float* __restrict__ dbc,
    const float* __restrict__ dWf, const float* __restrict__ dbf,
    const float* __restrict__ msort, const int* __restrict__ order,
    const float* __restrict__ fW1, const float* __restrict__ fb1,
    const float* __restrict__ fW2, const float* __restrict__ fb2,
    float* __restrict__ outp) {
  int b = blockIdx.x;
  int t = threadIdx.x;
  __shared__ float cmap[NCc];
  __shared__ float fmap[1024];
  __shared__ float cup[1024];
  __shared__ float hb[2][1024];
  // fine head: token j = t (sorted order), scatter to pixel order
  {
    const float* row = tokens + (size_t)(b * NTOK + NCc + t) * DD;
    float a = 0.f;
    #pragma unroll 8
    for (int d4 = 0; d4 < 32; ++d4) {
      float4 u = ((const float4*)row)[d4];
      float4 wv = ((const float4*)dWf)[d4];
      a += u.x * wv.x + u.y * wv.y + u.z * wv.z + u.w * wv.w;
    }
    a = (a + dbf[0]) * msort[b * NFf + t];
    fmap[order[b * NFf + t]] = a;   // 32->32 AC-bilinear is identity
  }
  if (t < NCc) {
    const float* row = tokens + (size_t)(b * NTOK + t) * DD;
    float a = 0.f;
    #pragma unroll 8
    for (int d4 = 0; d4 < 32; ++d4) {
      float4 u = ((const float4*)row)[d4];
      float4 wv = ((const float4*)dWc)[d4];
      a += u.x * wv.x + u.y * wv.y + u.z * wv.z + u.w * wv.w;
    }
    cmap[t] = a + dbc[0];
  }
  __syncthreads();
  // coarse 16->32 align-corners bilinear
  int y = t >> 5, x = t & 31;
  {
    float ys = y * (15.f / 31.f);
    float xs = x * (15.f / 31.f);
    int y0 = (int)floorf(ys); int y1 = min(y0 + 1, 15); float wy = ys - (float)y0;
    int x0 = (int)floorf(xs); int x1 = min(x0 + 1, 15); float wx = xs - (float)x0;
    cup[t] = cmap[y0 * 16 + x0] * (1.f - wy) * (1.f - wx)
           + cmap[y0 * 16 + x1] * (1.f - wy) * wx
           + cmap[y1 * 16 + x0] * wy * (1.f - wx)
           + cmap[y1 * 16 + x1] * wy * wx;
  }
  __syncthreads();
  // conv1 + relu
  for (int oc = 0; oc < 2; ++oc) {
    float a = fb1[oc];
    #pragma unroll
    for (int ic = 0; ic < 2; ++ic)
      #pragma unroll
      for (int ky = 0; ky < 3; ++ky)
        #pragma unroll
        for (int kx = 0; kx < 3; ++kx) {
          int yy = y + ky - 1, xx = x + kx - 1;
          float v = 0.f;
          if (yy >= 0 && yy < 32 && xx >= 0 && xx < 32)
            v = ic == 0 ? cup[yy * 32 + xx] : fmap[yy * 32 + xx];
          a += v * fW1[((oc * 2 + ic) * 3 + ky) * 3 + kx];
        }
    hb[oc][t] = fmaxf(a, 0.f);
  }
  __syncthreads();
  // conv2 -> out
  float a = fb2[0];
  #pragma unroll
  for (int ic = 0; ic < 2; ++ic)
    #pragma unroll
    for (int ky = 0; ky < 3; ++ky)
      #pragma unroll
      for (int kx = 0; kx < 3; ++kx) {
        int yy = y + ky - 1, xx = x + kx - 1;
        float v = (yy >= 0 && yy < 32 && xx >= 0 && xx < 32)
                      ? hb[ic][yy * 32 + xx] : 0.f;
        a += v * fW2[(ic * 3 + ky) * 3 + kx];
      }
  outp[b * 1024 + t] = a;
}

extern "C" void kernel_launch(void* const* d_in, const int* in_sizes, int n_in,
                              void* d_out, int out_size, void* d_ws, size_t ws_size,
                              hipStream_t stream) {
  const float* x    = (const float*)d_in[0];
  const float* Wpc  = (const float*)d_in[1];
  const float* bpc  = (const float*)d_in[2];
  const float* Wpf  = (const float*)d_in[3];
  const float* bpf  = (const float*)d_in[4];
  const float* te   = (const float*)d_in[5];
  const float* ln1g = (const float*)d_in[6];
  const float* ln1b = (const float*)d_in[7];
  const float* Wqkv = (const float*)d_in[8];
  const float* Wo   = (const float*)d_in[9];
  const float* bo   = (const float*)d_in[10];
  const float* ln2g = (const float*)d_in[11];
  const float* ln2b = (const float*)d_in[12];
  const float* W1   = (const float*)d_in[13];
  const float* b1   = (const float*)d_in[14];
  const float* W2   = (const float*)d_in[15];
  const float* b2   = (const float*)d_in[16];
  const float* dWc  = (const float*)d_in[17];
  const float* dbc  = (const float*)d_in[18];
  const float* dWf  = (const float*)d_in[19];
  const float* dbf  = (const float*)d_in[20];
  const float* fW1  = (const float*)d_in[21];
  const float* fb1  = (const float*)d_in[22];
  const float* fW2  = (const float*)d_in[23];
  const float* fb2  = (const float*)d_in[24];

  char* ws = (char*)d_ws;
  float* tokens = (float*)ws;                 ws += 1310720 * 4;   // fp32 [B*N,128]
  short* ybuf   = (short*)ws;                 ws += 1310720 * 2;   // bf16
  short* qkvb   = (short*)ws;                 ws += 3932160 * 2;   // bf16 [B*N,384]
  short* hbuf   = (short*)ws;                 ws += 2621440 * 2;   // bf16 [B*N,256]
  short* Opart  = (short*)ws;                 ws += (size_t)(Bx * HEADS * NQT * SPLIT) * 2048 * 2;
  float* Lpart  = (float*)ws;                 ws += (size_t)(Bx * HEADS * NQT * SPLIT) * 64 * 4;
  short* WtQKV  = (short*)ws;                 ws += 98304 * 2;     // [L][384][128]
  short* WtO    = (short*)ws;                 ws += 32768 * 2;     // [L][128][128]
  short* Wt1    = (short*)ws;                 ws += 65536 * 2;     // [L][256][128]
  short* Wt2    = (short*)ws;                 ws += 65536 * 2;     // [L][128][256]
  float* ebuf   = (float*)ws;                 ws += 8192 * 4;
  float* msort  = (float*)ws;                 ws += 8192 * 4;
  int*   order  = (int*)ws;                   ws += 8192 * 4;
  int*   inv    = (int*)ws;                   ws += 8192 * 4;

  const int M = Bx * NTOK;                    // 10240

  k_prologue<<<2560, 256, 0, stream>>>(x, Wpc, bpc, te, Wqkv, Wo, W1, W2,
                                       WtQKV, WtO, Wt1, Wt2, ebuf, tokens);
  k_edge_sort<<<Bx, 1024, 0, stream>>>(ebuf, order, inv, msort);
  k_fine<<<Bx * NFf, 128, 0, stream>>>(x, Wpf, bpf, te, inv, msort, tokens);

  for (int l = 0; l < LL; ++l) {
    k_ln_bf16<<<M / 4, 256, 0, stream>>>(tokens, ln1g + l * DD, ln1b + l * DD, ybuf);
    k_gemm_mfma<<<dim3(M / 64, 384 / 64), 256, 0, stream>>>(
        ybuf, WtQKV + (size_t)l * 49152, nullptr, nullptr, qkvb, 128, 384, 0);
    k_attn4<<<Bx * HEADS * NQT * SPLIT, 256, 0, stream>>>(qkvb, Opart, Lpart);
    k_gemm_wo<<<dim3(M / 64, 2), 256, 0, stream>>>(
        Opart, Lpart, WtO + (size_t)l * 16384, bo + l * DD, tokens);
    k_ln_bf16<<<M / 4, 256, 0, stream>>>(tokens, ln2g + l * DD, ln2b + l * DD, ybuf);
    k_gemm_mfma<<<dim3(M / 64, 256 / 64), 256, 0, stream>>>(
        ybuf, Wt1 + (size_t)l * 32768, b1 + l * 256, nullptr, hbuf, 128, 256, 1);
    k_gemm_mfma<<<dim3(M / 64, 128 / 64), 256, 0, stream>>>(
        hbuf, Wt2 + (size_t)l * 32768, b2 + l * DD, tokens, nullptr, 256, 128, 0);
  }

  k_decoder<<<Bx, 1024, 0, stream>>>(tokens, dWc, dbc, dWf, dbf, msort, order,
                                     fW1, fb1, fW2, fb2, (float*)d_out);
}

// Round 12
// 249.518 us; speedup vs baseline: 1.1229x; 1.0514x over previous
//
#include <hip/hip_runtime.h>
#include <math.h>

#define Bx 8
#define IMG 128
#define DD 128
#define HEADS 4
#define LL 2
#define PCc 8
#define PFf 4
#define HCc 16
#define NCc 256
#define HFf 32
#define NFf 1024
#define NTOK 1280
#define HD 32
#define SPLIT 4          // key-split factor for flash-decode attention
#define NQT 20           // NTOK/64 query tiles

typedef __attribute__((ext_vector_type(8))) short short8;
typedef __attribute__((ext_vector_type(4))) float f32x4;

__device__ __forceinline__ short f2bf(float f) {
  unsigned u = __builtin_bit_cast(unsigned, f);
  u += 0x7FFF + ((u >> 16) & 1);   // RNE
  return (short)(u >> 16);
}
__device__ __forceinline__ float bf2f(short s) {
  unsigned u = ((unsigned)(unsigned short)s) << 16;
  return __builtin_bit_cast(float, u);
}

// ---------------- batched prologue: [0,1024) prep_w, [1024,1536) sobel,
// [1536,2560) coarse patch embed (2 tokens/block)
__global__ __launch_bounds__(256) void k_prologue(const float* __restrict__ x,
    const float* __restrict__ Wpc, const float* __restrict__ bpc,
    const float* __restrict__ te,
    const float* __restrict__ Wqkv, const float* __restrict__ Wo,
    const float* __restrict__ W1, const float* __restrict__ W2,
    short* __restrict__ WtQKV, short* __restrict__ WtO,
    short* __restrict__ Wt1, short* __restrict__ Wt2,
    float* __restrict__ e, float* __restrict__ tokens) {
  int blk = blockIdx.x;
  int t = threadIdx.x;
  if (blk < 1024) {
    int idx = blk * 256 + t;   // 0 .. 262143
    int l = idx / 131072, r = idx % 131072;
    const float* src; short* dst; int N, off;
    if (r < 49152)      { src = Wqkv + l * 49152; dst = WtQKV + l * 49152; N = 384; off = r; }
    else if (r < 65536) { src = Wo + l * 16384;  dst = WtO + l * 16384;  N = 128; off = r - 49152; }
    else if (r < 98304) { src = W1 + l * 32768;  dst = Wt1 + l * 32768;  N = 256; off = r - 65536; }
    else                { src = W2 + l * 32768;  dst = Wt2 + l * 32768;  N = 128; off = r - 98304; }
    int k = off / N, n = off % N;
    int K = (r >= 98304) ? 256 : 128;
    dst[(size_t)n * K + k] = f2bf(src[off]);
  } else if (blk < 1536) {
    int bt = blk - 1024;
    int b = bt >> 6, tile = bt & 63;
    int ty = tile >> 3, tx = tile & 7;
    int ly = t >> 4, lx = t & 15;
    int py = ty * 16 + ly, px = tx * 16 + lx;
    const float* img = x + (size_t)b * IMG * IMG;
    float v[3][3];
    #pragma unroll
    for (int ky = 0; ky < 3; ++ky)
      #pragma unroll
      for (int kx = 0; kx < 3; ++kx) {
        int yy = py + ky - 1, xx = px + kx - 1;
        v[ky][kx] = (yy >= 0 && yy < IMG && xx >= 0 && xx < IMG)
                        ? img[yy * IMG + xx] : 0.f;
      }
    float gx = -v[0][0] + v[0][2] - 2.f * v[1][0] + 2.f * v[1][2] - v[2][0] + v[2][2];
    float gy = -v[0][0] - 2.f * v[0][1] - v[0][2] + v[2][0] + 2.f * v[2][1] + v[2][2];
    __shared__ float sm[256];
    sm[t] = sqrtf(gx * gx + gy * gy);
    __syncthreads();
    if (t < 16) {
      int cy = t >> 2, cx = t & 3;
      float s = 0.f;
      #pragma unroll
      for (int dy = 0; dy < 4; ++dy)
        #pragma unroll
        for (int dx = 0; dx < 4; ++dx) s += sm[(cy * 4 + dy) * 16 + cx * 4 + dx];
      e[b * NFf + (ty * 4 + cy) * 32 + tx * 4 + cx] = s * (1.f / 16.f);
    }
  } else {
    int bt = (blk - 1536) * 2 + (t >> 7);    // b*NC + tok
    int b = bt / NCc, tok = bt % NCc;
    int hc = tok / HCc, wc = tok % HCc;
    int half = t >> 7, d = t & 127;
    __shared__ float patch[2][PCc * PCc];
    if (d < PCc * PCc) {
      int pi = d / PCc, pj = d % PCc;
      patch[half][d] = x[(b * IMG + hc * PCc + pi) * IMG + wc * PCc + pj];
    }
    __syncthreads();
    float acc = bpc[d] + te[d];
    #pragma unroll 8
    for (int i = 0; i < PCc * PCc; ++i) acc += patch[half][i] * Wpc[i * DD + d];
    tokens[(size_t)(b * NTOK + tok) * DD + d] = acc;
  }
}

// ---------------- mask at per-image mean -> stable-sort order via ballot scan
__global__ __launch_bounds__(1024) void k_edge_sort(const float* __restrict__ e,
    int* __restrict__ order, int* __restrict__ inv, float* __restrict__ msort) {
  int b = blockIdx.x;
  int t = threadIdx.x;
  int lane = t & 63, wave = t >> 6;
  float ev = e[b * NFf + t];
  __shared__ float wsum[16];
  __shared__ int wcnt[16];
  float r = ev;
  #pragma unroll
  for (int o = 32; o > 0; o >>= 1) r += __shfl_xor(r, o, 64);
  if (lane == 0) wsum[wave] = r;
  __syncthreads();
  float tot = 0.f;
  #pragma unroll
  for (int i = 0; i < 16; ++i) tot += wsum[i];
  float mean = tot * (1.f / 1024.f);
  int m = (ev > mean) ? 1 : 0;
  unsigned long long bal = __ballot(m);
  if (lane == 0) wcnt[wave] = __popcll(bal);
  __syncthreads();
  int wbase = 0, total = 0;
  #pragma unroll
  for (int i = 0; i < 16; ++i) {
    int c = wcnt[i];
    if (i < wave) wbase += c;
    total += c;
  }
  unsigned long long below = (lane == 63) ? ~0ULL : ((1ULL << (lane + 1)) - 1);
  int incl = __popcll(bal & below);
  int eb = wbase + incl - m;       // edges strictly before t
  int pos = m ? eb : (total + t - eb);
  order[b * NFf + pos] = t;
  inv[b * NFf + t] = pos;
  msort[b * NFf + pos] = (float)m;
}

// ---------------- fine patch embed + direct scatter into tokens[:, 256:]
__global__ __launch_bounds__(128) void k_fine(const float* __restrict__ x,
    const float* __restrict__ Wpf, const float* __restrict__ bpf,
    const float* __restrict__ te, const int* __restrict__ inv,
    const float* __restrict__ msort, float* __restrict__ tokens) {
  int blk = blockIdx.x;            // b*NF + t
  int b = blk / NFf, t = blk % NFf;
  int hf = t / HFf, wf = t % HFf;
  int d = threadIdx.x;
  __shared__ float patch[PFf * PFf];
  if (d < PFf * PFf) {
    int pi = d / PFf, pj = d % PFf;
    patch[d] = x[(b * IMG + hf * PFf + pi) * IMG + wf * PFf + pj];
  }
  __syncthreads();
  float acc = bpf[d];
  #pragma unroll
  for (int i = 0; i < PFf * PFf; ++i) acc += patch[i] * Wpf[i * DD + d];
  int pos = inv[b * NFf + t];
  float mk = msort[b * NFf + pos];
  tokens[(size_t)(b * NTOK + NCc + pos) * DD + d] = acc * mk + te[DD + d];
}

// ---------------- LayerNorm over D=128, one wave per row, out bf16
// (used ONCE: layer-0 ln1. Other LNs are producer-fused into wo/w2 epilogues.)
__global__ __launch_bounds__(256) void k_ln_bf16(const float* __restrict__ inp,
    const float* __restrict__ g, const float* __restrict__ bb,
    short* __restrict__ outp) {
  int row = blockIdx.x * 4 + (threadIdx.x >> 6);
  int lane = threadIdx.x & 63;
  float2 v = ((const float2*)(inp + (size_t)row * DD))[lane];
  float s = v.x + v.y;
  #pragma unroll
  for (int o = 32; o > 0; o >>= 1) s += __shfl_xor(s, o, 64);
  float mean = s * (1.f / 128.f);
  float cx = v.x - mean, cy = v.y - mean;
  float q = cx * cx + cy * cy;
  #pragma unroll
  for (int o = 32; o > 0; o >>= 1) q += __shfl_xor(q, o, 64);
  float rstd = rsqrtf(q * (1.f / 128.f) + 1e-5f);
  float2 gg = ((const float2*)g)[lane];
  float2 bv = ((const float2*)bb)[lane];
  int p = (int)(unsigned short)f2bf(cx * rstd * gg.x + bv.x)
        | ((int)(unsigned short)f2bf(cy * rstd * gg.y + bv.y) << 16);
  ((int*)(outp + (size_t)row * DD))[lane] = p;
}

// ---------------- MFMA GEMM, async DMA staging with XOR-swizzled LDS layout
__global__ __launch_bounds__(256) void k_gemm_mfma(const short* __restrict__ A,
    const short* __restrict__ Wt, const float* __restrict__ bias,
    float* __restrict__ Cf, short* __restrict__ Cb, int K, int N, int do_gelu) {
  __shared__ short Alds[64 * 128];
  __shared__ short Blds[64 * 128];
  int row0 = blockIdx.x * 64, col0 = blockIdx.y * 64;
  int t = threadIdx.x;
  int lane = t & 63, w = t >> 6;
  int m = lane & 15, quad = lane >> 4;
  int lrow = lane >> 4, jphys = lane & 15;   // staging sub-addressing
  f32x4 zero = {0.f, 0.f, 0.f, 0.f};
  f32x4 acc[4] = {zero, zero, zero, zero};

  for (int kb = 0; kb < K; kb += 128) {
    __syncthreads();
    #pragma unroll
    for (int j = 0; j < 4; ++j) {
      int c = j * 4 + w;               // chunk-group 0..15, wave-uniform
      int r = c * 4 + lrow;            // tile row this lane fetches
      int jlog = jphys ^ (r & 15);     // XOR swizzle
      __builtin_amdgcn_global_load_lds(
          (const unsigned*)&A[(size_t)(row0 + r) * K + kb + jlog * 8],
          (unsigned*)&Alds[c * 512], 16, 0, 0);
      __builtin_amdgcn_global_load_lds(
          (const unsigned*)&Wt[(size_t)(col0 + r) * K + kb + jlog * 8],
          (unsigned*)&Blds[c * 512], 16, 0, 0);
    }
    __syncthreads();
    #pragma unroll
    for (int ks = 0; ks < 4; ++ks) {   // logical chunk = quad + ks*4
      int pc = ((quad + ks * 4) ^ m) * 8;
      short8 af = *(const short8*)&Alds[(w * 16 + m) * 128 + pc];
      #pragma unroll
      for (int nt = 0; nt < 4; ++nt) {
        short8 bf = *(const short8*)&Blds[(nt * 16 + m) * 128 + pc];
        acc[nt] = __builtin_amdgcn_mfma_f32_16x16x32_bf16(af, bf, acc[nt], 0, 0, 0);
      }
    }
  }
  #pragma unroll
  for (int nt = 0; nt < 4; ++nt) {
    int col = col0 + nt * 16 + m;
    float bv = bias ? bias[col] : 0.f;
    #pragma unroll
    for (int r = 0; r < 4; ++r) {
      int row = row0 + w * 16 + quad * 4 + r;
      float v = acc[nt][r] + bv;
      if (do_gelu) v = 0.5f * v * (1.f + erff(v * 0.70710678118654752f));
      if (Cf) Cf[(size_t)row * N + col] += v;
      else    Cb[(size_t)row * N + col] = f2bf(v);
    }
  }
}

// ---------------- Wo GEMM: split-K combine A + residual + fused LN -> ybuf
// tile 32 rows x 128 cols (full row per block); grid M/32; 4 waves:
// wave w = (row-tile rt = w>>1) x (col-half ch = w&1)
__global__ __launch_bounds__(256) void k_gemm_wo_ln(const short* __restrict__ Opart,
    const float* __restrict__ Lpart, const short* __restrict__ Wt,
    const float* __restrict__ bias, float* __restrict__ tokens,
    const float* __restrict__ lng, const float* __restrict__ lnb,
    short* __restrict__ ybuf) {
  __shared__ short Alds[32 * 136];
  __shared__ short Blds[128 * 128];
  __shared__ float pls[2][32], plq[2][32];
  int row0 = blockIdx.x * 32;
  int b = row0 / NTOK;
  int rloc = row0 % NTOK;
  int qt = rloc >> 6, qoff = rloc & 63;   // 0 or 32
  int t = threadIdx.x;
  int lane = t & 63, w = t >> 6;
  int m = lane & 15, quad = lane >> 4;
  int rt = w >> 1, ch = w & 1;
  int lrow = lane >> 4, jphys = lane & 15;
  f32x4 zero = {0.f, 0.f, 0.f, 0.f};
  f32x4 acc[4] = {zero, zero, zero, zero};

  // ---- B staging (DMA, all 128 Wt rows), overlaps A combine below
  #pragma unroll
  for (int j = 0; j < 8; ++j) {
    int c = j * 4 + w;                 // 0..31 (4 rows each)
    int r = c * 4 + lrow;
    int jlog = jphys ^ (r & 15);
    __builtin_amdgcn_global_load_lds(
        (const unsigned*)&Wt[(size_t)r * 128 + jlog * 8],
        (unsigned*)&Blds[c * 512], 16, 0, 0);
  }
  // ---- A staging: combine split-K partials, normalize by L, write bf16
  #pragma unroll
  for (int it = 0; it < 2; ++it) {
    int idx = t + it * 256;            // 512 short8 chunks (32 rows x 16)
    int q = idx >> 4, j = idx & 15;
    int hh = j >> 2, dd = (j & 3) * 8;
    int qg = qoff + q;                 // q within the 64-row attention tile
    size_t pb = ((size_t)(b * HEADS + hh) * NQT + qt) * SPLIT;
    float L = Lpart[(pb + 0) * 64 + qg] + Lpart[(pb + 1) * 64 + qg]
            + Lpart[(pb + 2) * 64 + qg] + Lpart[(pb + 3) * 64 + qg];
    float o[8] = {0, 0, 0, 0, 0, 0, 0, 0};
    #pragma unroll
    for (int sk = 0; sk < SPLIT; ++sk) {
      short8 po = *(const short8*)&Opart[(pb + sk) * 2048 + qg * 32 + dd];
      #pragma unroll
      for (int i = 0; i < 8; ++i) o[i] += bf2f(po[i]);
    }
    float rs = 1.f / L;
    short8 ov;
    #pragma unroll
    for (int i = 0; i < 8; ++i) ov[i] = f2bf(o[i] * rs);
    *(short8*)&Alds[q * 136 + j * 8] = ov;
  }
  __syncthreads();
  #pragma unroll
  for (int ks = 0; ks < 4; ++ks) {
    short8 af = *(const short8*)&Alds[(rt * 16 + m) * 136 + quad * 8 + ks * 32];
    int pc = ((quad + ks * 4) ^ m) * 8;
    #pragma unroll
    for (int nt = 0; nt < 4; ++nt) {
      short8 bf = *(const short8*)&Blds[(ch * 64 + nt * 16 + m) * 128 + pc];
      acc[nt] = __builtin_amdgcn_mfma_f32_16x16x32_bf16(af, bf, acc[nt], 0, 0, 0);
    }
  }
  // ---- epilogue: residual add (write tokens) + LN across the full row
  float v[4][4];
  #pragma unroll
  for (int nt = 0; nt < 4; ++nt) {
    int col = ch * 64 + nt * 16 + m;
    float bv = bias[col];
    #pragma unroll
    for (int r = 0; r < 4; ++r) {
      int row = row0 + rt * 16 + quad * 4 + r;
      float val = acc[nt][r] + bv + tokens[(size_t)row * DD + col];
      tokens[(size_t)row * DD + col] = val;
      v[nt][r] = val;
    }
  }
  #pragma unroll
  for (int r = 0; r < 4; ++r) {
    float s = v[0][r] + v[1][r] + v[2][r] + v[3][r];
    float q = v[0][r] * v[0][r] + v[1][r] * v[1][r]
            + v[2][r] * v[2][r] + v[3][r] * v[3][r];
    #pragma unroll
    for (int o = 1; o < 16; o <<= 1) { s += __shfl_xor(s, o); q += __shfl_xor(q, o); }
    if (m == 0) {
      int lr = rt * 16 + quad * 4 + r;
      pls[ch][lr] = s;
      plq[ch][lr] = q;
    }
  }
  __syncthreads();
  #pragma unroll
  for (int r = 0; r < 4; ++r) {
    int lr = rt * 16 + quad * 4 + r;
    float S = pls[0][lr] + pls[1][lr];
    float Q = plq[0][lr] + plq[1][lr];
    float mean = S * (1.f / 128.f);
    float var = Q * (1.f / 128.f) - mean * mean;
    float rstd = rsqrtf(var + 1e-5f);
    int row = row0 + lr;
    #pragma unroll
    for (int nt = 0; nt < 4; ++nt) {
      int col = ch * 64 + nt * 16 + m;
      ybuf[(size_t)row * DD + col] = f2bf((v[nt][r] - mean) * rstd * lng[col] + lnb[col]);
    }
  }
}

// ---------------- W2 GEMM (K=256, N=128): residual + optional fused LN -> ybuf
// same 32x128 full-row tiling as k_gemm_wo_ln; A bf16 via DMA
__global__ __launch_bounds__(256) void k_gemm_w2_ln(const short* __restrict__ A,
    const short* __restrict__ Wt, const float* __restrict__ bias,
    float* __restrict__ tokens, const float* __restrict__ lng,
    const float* __restrict__ lnb, short* __restrict__ ybuf) {
  __shared__ short Alds[32 * 128];
  __shared__ short Blds[128 * 128];
  __shared__ float pls[2][32], plq[2][32];
  int row0 = blockIdx.x * 32;
  int t = threadIdx.x;
  int lane = t & 63, w = t >> 6;
  int m = lane & 15, quad = lane >> 4;
  int rt = w >> 1, ch = w & 1;
  int lrow = lane >> 4, jphys = lane & 15;
  f32x4 zero = {0.f, 0.f, 0.f, 0.f};
  f32x4 acc[4] = {zero, zero, zero, zero};

  for (int kb = 0; kb < 256; kb += 128) {
    __syncthreads();
    #pragma unroll
    for (int j = 0; j < 2; ++j) {      // A: 32 rows
      int c = j * 4 + w;               // 0..7
      int r = c * 4 + lrow;
      int jlog = jphys ^ (r & 15);
      __builtin_amdgcn_global_load_lds(
          (const unsigned*)&A[(size_t)(row0 + r) * 256 + kb + jlog * 8],
          (unsigned*)&Alds[c * 512], 16, 0, 0);
    }
    #pragma unroll
    for (int j = 0; j < 8; ++j) {      // B: 128 rows
      int c = j * 4 + w;               // 0..31
      int r = c * 4 + lrow;
      int jlog = jphys ^ (r & 15);
      __builtin_amdgcn_global_load_lds(
          (const unsigned*)&Wt[(size_t)r * 256 + kb + jlog * 8],
          (unsigned*)&Blds[c * 512], 16, 0, 0);
    }
    __syncthreads();
    #pragma unroll
    for (int ks = 0; ks < 4; ++ks) {
      int pc = ((quad + ks * 4) ^ m) * 8;
      short8 af = *(const short8*)&Alds[(rt * 16 + m) * 128 + pc];
      #pragma unroll
      for (int nt = 0; nt < 4; ++nt) {
        short8 bf = *(const short8*)&Blds[(ch * 64 + nt * 16 + m) * 128 + pc];
        acc[nt] = __builtin_amdgcn_mfma_f32_16x16x32_bf16(af, bf, acc[nt], 0, 0, 0);
      }
    }
  }
  // ---- epilogue: residual add (write tokens) + optional LN across full row
  float v[4][4];
  #pragma unroll
  for (int nt = 0; nt < 4; ++nt) {
    int col = ch * 64 + nt * 16 + m;
    float bv = bias[col];
    #pragma unroll
    for (int r = 0; r < 4; ++r) {
      int row = row0 + rt * 16 + quad * 4 + r;
      float val = acc[nt][r] + bv + tokens[(size_t)row * DD + col];
      tokens[(size_t)row * DD + col] = val;
      v[nt][r] = val;
    }
  }
  if (ybuf) {
    #pragma unroll
    for (int r = 0; r < 4; ++r) {
      float s = v[0][r] + v[1][r] + v[2][r] + v[3][r];
      float q = v[0][r] * v[0][r] + v[1][r] * v[1][r]
              + v[2][r] * v[2][r] + v[3][r] * v[3][r];
      #pragma unroll
      for (int o = 1; o < 16; o <<= 1) { s += __shfl_xor(s, o); q += __shfl_xor(q, o); }
      if (m == 0) {
        int lr = rt * 16 + quad * 4 + r;
        pls[ch][lr] = s;
        plq[ch][lr] = q;
      }
    }
    __syncthreads();
    #pragma unroll
    for (int r = 0; r < 4; ++r) {
      int lr = rt * 16 + quad * 4 + r;
      float S = pls[0][lr] + pls[1][lr];
      float Q = plq[0][lr] + plq[1][lr];
      float mean = S * (1.f / 128.f);
      float var = Q * (1.f / 128.f) - mean * mean;
      float rstd = rsqrtf(var + 1e-5f);
      int row = row0 + lr;
      #pragma unroll
      for (int nt = 0; nt < 4; ++nt) {
        int col = ch * 64 + nt * 16 + m;
        ybuf[(size_t)row * DD + col] = f2bf((v[nt][r] - mean) * rstd * lng[col] + lnb[col]);
      }
    }
  }
}

// ---------------- flash attention (R7 config): split-K, fixed-max softmax,
// swizzled Ks, two barriers/stage (implicit wave overlap does the pipelining)
__global__ __launch_bounds__(256) void k_attn4(const short* __restrict__ qkv,
    short* __restrict__ Opart, float* __restrict__ Lpart) {
  __shared__ short Ks[64 * 32];      // [key][d], DMA, chunk swizzle f(k)=(k>>1)&3
  __shared__ short Vt[32 * 74];      // [d][key], stride 74 (free scatter+gather)
  __shared__ short Pl[4][16 * 74];   // per-wave P [q][key]

  int sk = blockIdx.x % SPLIT;
  int qt = (blockIdx.x / SPLIT) % NQT;
  int h  = (blockIdx.x / (SPLIT * NQT)) % HEADS;
  int b  = blockIdx.x / (SPLIT * NQT * HEADS);
  int t = threadIdx.x;
  int lane = t & 63, w = t >> 6;
  int m = lane & 15, quad = lane >> 4;
  int q0 = qt * 64 + w * 16;

  const float scale = 0.17677669529663687f;  // 1/sqrt(32), folded into Q
  short8 qraw = *(const short8*)(qkv + ((size_t)(b * NTOK) + q0 + m) * 384 + h * HD + quad * 8);
  short8 qf;
  #pragma unroll
  for (int j = 0; j < 8; ++j) qf[j] = f2bf(bf2f(qraw[j]) * scale);

  f32x4 zero = {0.f, 0.f, 0.f, 0.f};
  f32x4 Oacc[2] = {zero, zero};
  float psum[4] = {0.f, 0.f, 0.f, 0.f};

  int skey = t >> 2, sdseg = t & 3;  // staging: key 0..63, 8 dims each
  int jlogK = sdseg ^ ((skey >> 1) & 3);
  const short* kstage = qkv + ((size_t)(b * NTOK) + skey) * 384 + 128 + h * HD + jlogK * 8;
  const short* vstage = qkv + ((size_t)(b * NTOK) + skey) * 384 + 256 + h * HD + sdseg * 8;
  int kswz = (quad ^ ((m >> 1) & 3)) * 8;   // read-side physical chunk offset

  for (int s = sk * 5; s < sk * 5 + 5; ++s) {
    __syncthreads();
    __builtin_amdgcn_global_load_lds((const unsigned*)(kstage + (size_t)s * 64 * 384),
                                     (unsigned*)&Ks[w * 512], 16, 0, 0);
    short8 vf = *(const short8*)(vstage + (size_t)s * 64 * 384);
    #pragma unroll
    for (int j = 0; j < 8; ++j) Vt[(sdseg * 8 + j) * 74 + skey] = vf[j];
    __syncthreads();

    // S = Q K^T (C-layout: row=4*quad+reg, col=m); Q pre-scaled
    f32x4 sc[4];
    #pragma unroll
    for (int ct = 0; ct < 4; ++ct) {
      short8 kfrag = *(const short8*)&Ks[(ct * 16 + m) * 32 + kswz];
      sc[ct] = __builtin_amdgcn_mfma_f32_16x16x32_bf16(qf, kfrag, zero, 0, 0, 0);
    }
    // fixed-max softmax: p = exp(s); l accumulated from TRUNCATED p (bias-free)
    #pragma unroll
    for (int ct = 0; ct < 4; ++ct)
      #pragma unroll
      for (int r = 0; r < 4; ++r) {
        float p = __expf(sc[ct][r]);
        unsigned u = __builtin_bit_cast(unsigned, p);
        psum[r] += __builtin_bit_cast(float, u & 0xffff0000u);
        Pl[w][(quad * 4 + r) * 74 + ct * 16 + m] = (short)(u >> 16);
      }
    // O += P @ V
    #pragma unroll
    for (int ks = 0; ks < 2; ++ks) {
      short8 pfrag = *(const short8*)&Pl[w][m * 74 + ks * 32 + quad * 8];
      #pragma unroll
      for (int nt = 0; nt < 2; ++nt) {
        short8 vfrag = *(const short8*)&Vt[(nt * 16 + m) * 74 + ks * 32 + quad * 8];
        Oacc[nt] = __builtin_amdgcn_mfma_f32_16x16x32_bf16(pfrag, vfrag, Oacc[nt], 0, 0, 0);
      }
    }
  }
  // single final ladder per row; write partial O (unnormalized) + l
  #pragma unroll
  for (int r = 0; r < 4; ++r) {
    float ssum = psum[r];
    #pragma unroll
    for (int o = 1; o < 16; o <<= 1) ssum += __shfl_xor(ssum, o);
    int qloc = w * 16 + quad * 4 + r;
    #pragma unroll
    for (int nt = 0; nt < 2; ++nt)
      Opart[(size_t)blockIdx.x * 2048 + qloc * 32 + nt * 16 + m] = f2bf(Oacc[nt][r]);
    if (m == 0) Lpart[(size_t)blockIdx.x * 64 + qloc] = ssum;
  }
}

// ---------------- fused decoder: coarse head + bilinear, fine head + scatter,
// conv3x3+relu+conv3x3 — one block per image, everything in LDS
__global__ __launch_bounds__(1024) void k_decoder(const float* __restrict__ tokens,
    const float* __restrict__ dWc, const float* __restrict__ dbc,
    const float* __restrict__ dWf, const float* __restrict__ dbf,
    const float* __restrict__ msort, const int* __restrict__ order,
    const float* __restrict__ fW1, const float* __restrict__ fb1,
    const float* __restrict__ fW2, const float* __restrict__ fb2,
    float* __restrict__ outp) {
  int b = blockIdx.x;
  int t = threadIdx.x;
  __shared__ float cmap[NCc];
  __shared__ float fmap[1024];
  __shared__ float cup[1024];
  __shared__ float hb[2][1024];
  {
    const float* row = tokens + (size_t)(b * NTOK + NCc + t) * DD;
    float a = 0.f;
    #pragma unroll 8
    for (int d4 = 0; d4 < 32; ++d4) {
      float4 u = ((const float4*)row)[d4];
      float4 wv = ((const float4*)dWf)[d4];
      a += u.x * wv.x + u.y * wv.y + u.z * wv.z + u.w * wv.w;
    }
    a = (a + dbf[0]) * msort[b * NFf + t];
    fmap[order[b * NFf + t]] = a;   // 32->32 AC-bilinear is identity
  }
  if (t < NCc) {
    const float* row = tokens + (size_t)(b * NTOK + t) * DD;
    float a = 0.f;
    #pragma unroll 8
    for (int d4 = 0; d4 < 32; ++d4) {
      float4 u = ((const float4*)row)[d4];
      float4 wv = ((const float4*)dWc)[d4];
      a += u.x * wv.x + u.y * wv.y + u.z * wv.z + u.w * wv.w;
    }
    cmap[t] = a + dbc[0];
  }
  __syncthreads();
  int y = t >> 5, x = t & 31;
  {
    float ys = y * (15.f / 31.f);
    float xs = x * (15.f / 31.f);
    int y0 = (int)floorf(ys); int y1 = min(y0 + 1, 15); float wy = ys - (float)y0;
    int x0 = (int)floorf(xs); int x1 = min(x0 + 1, 15); float wx = xs - (float)x0;
    cup[t] = cmap[y0 * 16 + x0] * (1.f - wy) * (1.f - wx)
           + cmap[y0 * 16 + x1] * (1.f - wy) * wx
           + cmap[y1 * 16 + x0] * wy * (1.f - wx)
           + cmap[y1 * 16 + x1] * wy * wx;
  }
  __syncthreads();
  for (int oc = 0; oc < 2; ++oc) {
    float a = fb1[oc];
    #pragma unroll
    for (int ic = 0; ic < 2; ++ic)
      #pragma unroll
      for (int ky = 0; ky < 3; ++ky)
        #pragma unroll
        for (int kx = 0; kx < 3; ++kx) {
          int yy = y + ky - 1, xx = x + kx - 1;
          float v = 0.f;
          if (yy >= 0 && yy < 32 && xx >= 0 && xx < 32)
            v = ic == 0 ? cup[yy * 32 + xx] : fmap[yy * 32 + xx];
          a += v * fW1[((oc * 2 + ic) * 3 + ky) * 3 + kx];
        }
    hb[oc][t] = fmaxf(a, 0.f);
  }
  __syncthreads();
  float a = fb2[0];
  #pragma unroll
  for (int ic = 0; ic < 2; ++ic)
    #pragma unroll
    for (int ky = 0; ky < 3; ++ky)
      #pragma unroll
      for (int kx = 0; kx < 3; ++kx) {
        int yy = y + ky - 1, xx = x + kx - 1;
        float v = (yy >= 0 && yy < 32 && xx >= 0 && xx < 32)
                      ? hb[ic][yy * 32 + xx] : 0.f;
        a += v * fW2[(ic * 3 + ky) * 3 + kx];
      }
  outp[b * 1024 + t] = a;
}

extern "C" void kernel_launch(void* const* d_in, const int* in_sizes, int n_in,
                              void* d_out, int out_size, void* d_ws, size_t ws_size,
                              hipStream_t stream) {
  const float* x    = (const float*)d_in[0];
  const float* Wpc  = (const float*)d_in[1];
  const float* bpc  = (const float*)d_in[2];
  const float* Wpf  = (const float*)d_in[3];
  const float* bpf  = (const float*)d_in[4];
  const float* te   = (const float*)d_in[5];
  const float* ln1g = (const float*)d_in[6];
  const float* ln1b = (const float*)d_in[7];
  const float* Wqkv = (const float*)d_in[8];
  const float* Wo   = (const float*)d_in[9];
  const float* bo   = (const float*)d_in[10];
  const float* ln2g = (const float*)d_in[11];
  const float* ln2b = (const float*)d_in[12];
  const float* W1   = (const float*)d_in[13];
  const float* b1   = (const float*)d_in[14];
  const float* W2   = (const float*)d_in[15];
  const float* b2   = (const float*)d_in[16];
  const float* dWc  = (const float*)d_in[17];
  const float* dbc  = (const float*)d_in[18];
  const float* dWf  = (const float*)d_in[19];
  const float* dbf  = (const float*)d_in[20];
  const float* fW1  = (const float*)d_in[21];
  const float* fb1  = (const float*)d_in[22];
  const float* fW2  = (const float*)d_in[23];
  const float* fb2  = (const float*)d_in[24];

  char* ws = (char*)d_ws;
  float* tokens = (float*)ws;                 ws += 1310720 * 4;   // fp32 [B*N,128]
  short* ybuf   = (short*)ws;                 ws += 1310720 * 2;   // bf16
  short* qkvb   = (short*)ws;                 ws += 3932160 * 2;   // bf16 [B*N,384]
  short* hbuf   = (short*)ws;                 ws += 2621440 * 2;   // bf16 [B*N,256]
  short* Opart  = (short*)ws;                 ws += (size_t)(Bx * HEADS * NQT * SPLIT) * 2048 * 2;
  float* Lpart  = (float*)ws;                 ws += (size_t)(Bx * HEADS * NQT * SPLIT) * 64 * 4;
  short* WtQKV  = (short*)ws;                 ws += 98304 * 2;     // [L][384][128]
  short* WtO    = (short*)ws;                 ws += 32768 * 2;     // [L][128][128]
  short* Wt1    = (short*)ws;                 ws += 65536 * 2;     // [L][256][128]
  short* Wt2    = (short*)ws;                 ws += 65536 * 2;     // [L][128][256]
  float* ebuf   = (float*)ws;                 ws += 8192 * 4;
  float* msort  = (float*)ws;                 ws += 8192 * 4;
  int*   order  = (int*)ws;                   ws += 8192 * 4;
  int*   inv    = (int*)ws;                   ws += 8192 * 4;

  const int M = Bx * NTOK;                    // 10240

  k_prologue<<<2560, 256, 0, stream>>>(x, Wpc, bpc, te, Wqkv, Wo, W1, W2,
                                       WtQKV, WtO, Wt1, Wt2, ebuf, tokens);
  k_edge_sort<<<Bx, 1024, 0, stream>>>(ebuf, order, inv, msort);
  k_fine<<<Bx * NFf, 128, 0, stream>>>(x, Wpf, bpf, te, inv, msort, tokens);
  k_ln_bf16<<<M / 4, 256, 0, stream>>>(tokens, ln1g, ln1b, ybuf);  // layer-0 ln1

  for (int l = 0; l < LL; ++l) {
    k_gemm_mfma<<<dim3(M / 64, 384 / 64), 256, 0, stream>>>(
        ybuf, WtQKV + (size_t)l * 49152, nullptr, nullptr, qkvb, 128, 384, 0);
    k_attn4<<<Bx * HEADS * NQT * SPLIT, 256, 0, stream>>>(qkvb, Opart, Lpart);
    k_gemm_wo_ln<<<M / 32, 256, 0, stream>>>(
        Opart, Lpart, WtO + (size_t)l * 16384, bo + l * DD, tokens,
        ln2g + l * DD, ln2b + l * DD, ybuf);
    k_gemm_mfma<<<dim3(M / 64, 256 / 64), 256, 0, stream>>>(
        ybuf, Wt1 + (size_t)l * 32768, b1 + l * 256, nullptr, hbuf, 128, 256, 1);
    k_gemm_w2_ln<<<M / 32, 256, 0, stream>>>(
        hbuf, Wt2 + (size_t)l * 32768, b2 + l * DD, tokens,
        (l == 0) ? (ln1g + DD) : nullptr, (l == 0) ? (ln1b + DD) : nullptr,
        (l == 0) ? ybuf : nullptr);
  }

  k_decoder<<<Bx, 1024, 0, stream>>>(tokens, dWc, dbc, dWf, dbf, msort, order,
                                     fW1, fb1, fW2, fb2, (float*)d_out);
}

// Round 13
// 247.695 us; speedup vs baseline: 1.1312x; 1.0074x over previous
//
#include <hip/hip_runtime.h>
#include <math.h>

#define Bx 8
#define IMG 128
#define DD 128
#define HEADS 4
#define LL 2
#define PCc 8
#define PFf 4
#define HCc 16
#define NCc 256
#define HFf 32
#define NFf 1024
#define NTOK 1280
#define HD 32
#define SPLIT 4          // key-split factor for flash-decode attention
#define NQT 20           // NTOK/64 query tiles

typedef __attribute__((ext_vector_type(8))) short short8;
typedef __attribute__((ext_vector_type(4))) float f32x4;

__device__ __forceinline__ short f2bf(float f) {
  unsigned u = __builtin_bit_cast(unsigned, f);
  u += 0x7FFF + ((u >> 16) & 1);   // RNE
  return (short)(u >> 16);
}
__device__ __forceinline__ float bf2f(short s) {
  unsigned u = ((unsigned)(unsigned short)s) << 16;
  return __builtin_bit_cast(float, u);
}

// ---------------- batched prologue: [0,1024) prep_w, [1024,1536) sobel,
// [1536,2560) coarse embed (2 tok/block), [2560,6656) fine embed -> fineb
// (fine embed is sort-independent: raw patch@Wpf+bpf, no mask/type-embed)
__global__ __launch_bounds__(256) void k_prologue(const float* __restrict__ x,
    const float* __restrict__ Wpc, const float* __restrict__ bpc,
    const float* __restrict__ Wpf, const float* __restrict__ bpf,
    const float* __restrict__ te,
    const float* __restrict__ Wqkv, const float* __restrict__ Wo,
    const float* __restrict__ W1, const float* __restrict__ W2,
    short* __restrict__ WtQKV, short* __restrict__ WtO,
    short* __restrict__ Wt1, short* __restrict__ Wt2,
    float* __restrict__ e, float* __restrict__ tokens,
    float* __restrict__ fineb) {
  int blk = blockIdx.x;
  int t = threadIdx.x;
  if (blk < 1024) {
    // ---- weight prep: transpose + bf16
    int idx = blk * 256 + t;   // 0 .. 262143
    int l = idx / 131072, r = idx % 131072;
    const float* src; short* dst; int N, off;
    if (r < 49152)      { src = Wqkv + l * 49152; dst = WtQKV + l * 49152; N = 384; off = r; }
    else if (r < 65536) { src = Wo + l * 16384;  dst = WtO + l * 16384;  N = 128; off = r - 49152; }
    else if (r < 98304) { src = W1 + l * 32768;  dst = Wt1 + l * 32768;  N = 256; off = r - 65536; }
    else                { src = W2 + l * 32768;  dst = Wt2 + l * 32768;  N = 128; off = r - 98304; }
    int k = off / N, n = off % N;
    int K = (r >= 98304) ? 256 : 128;
    dst[(size_t)n * K + k] = f2bf(src[off]);
  } else if (blk < 1536) {
    // ---- sobel + 4x4 avgpool -> cell energy
    int bt = blk - 1024;
    int b = bt >> 6, tile = bt & 63;
    int ty = tile >> 3, tx = tile & 7;
    int ly = t >> 4, lx = t & 15;
    int py = ty * 16 + ly, px = tx * 16 + lx;
    const float* img = x + (size_t)b * IMG * IMG;
    float v[3][3];
    #pragma unroll
    for (int ky = 0; ky < 3; ++ky)
      #pragma unroll
      for (int kx = 0; kx < 3; ++kx) {
        int yy = py + ky - 1, xx = px + kx - 1;
        v[ky][kx] = (yy >= 0 && yy < IMG && xx >= 0 && xx < IMG)
                        ? img[yy * IMG + xx] : 0.f;
      }
    float gx = -v[0][0] + v[0][2] - 2.f * v[1][0] + 2.f * v[1][2] - v[2][0] + v[2][2];
    float gy = -v[0][0] - 2.f * v[0][1] - v[0][2] + v[2][0] + 2.f * v[2][1] + v[2][2];
    __shared__ float sm[256];
    sm[t] = sqrtf(gx * gx + gy * gy);
    __syncthreads();
    if (t < 16) {
      int cy = t >> 2, cx = t & 3;
      float s = 0.f;
      #pragma unroll
      for (int dy = 0; dy < 4; ++dy)
        #pragma unroll
        for (int dx = 0; dx < 4; ++dx) s += sm[(cy * 4 + dy) * 16 + cx * 4 + dx];
      e[b * NFf + (ty * 4 + cy) * 32 + tx * 4 + cx] = s * (1.f / 16.f);
    }
  } else if (blk < 2560) {
    // ---- coarse patch embed, 2 tokens per block
    int bt = (blk - 1536) * 2 + (t >> 7);    // b*NC + tok
    int b = bt / NCc, tok = bt % NCc;
    int hc = tok / HCc, wc = tok % HCc;
    int half = t >> 7, d = t & 127;
    __shared__ float patch[2][PCc * PCc];
    if (d < PCc * PCc) {
      int pi = d / PCc, pj = d % PCc;
      patch[half][d] = x[(b * IMG + hc * PCc + pi) * IMG + wc * PCc + pj];
    }
    __syncthreads();
    float acc = bpc[d] + te[d];
    #pragma unroll 8
    for (int i = 0; i < PCc * PCc; ++i) acc += patch[half][i] * Wpc[i * DD + d];
    tokens[(size_t)(b * NTOK + tok) * DD + d] = acc;
  } else {
    // ---- fine patch embed, 2 tokens per block -> fineb (unsorted, unmasked)
    int ft = (blk - 2560) * 2 + (t >> 7);    // global fine token 0..8191
    int b = ft >> 10, tloc = ft & 1023;
    int hf = tloc >> 5, wf = tloc & 31;
    int half = t >> 7, d = t & 127;
    __shared__ float patch[2][PFf * PFf];
    if (d < PFf * PFf) {
      int pi = d / PFf, pj = d % PFf;
      patch[half][d] = x[(b * IMG + hf * PFf + pi) * IMG + wf * PFf + pj];
    }
    __syncthreads();
    float acc = bpf[d];
    #pragma unroll
    for (int i = 0; i < PFf * PFf; ++i) acc += patch[half][i] * Wpf[i * DD + d];
    fineb[(size_t)(b * NFf + tloc) * DD + d] = acc;
  }
}

// ---------------- mask at per-image mean -> stable-sort order via ballot scan
__global__ __launch_bounds__(1024) void k_edge_sort(const float* __restrict__ e,
    int* __restrict__ order, float* __restrict__ msort) {
  int b = blockIdx.x;
  int t = threadIdx.x;
  int lane = t & 63, wave = t >> 6;
  float ev = e[b * NFf + t];
  __shared__ float wsum[16];
  __shared__ int wcnt[16];
  float r = ev;
  #pragma unroll
  for (int o = 32; o > 0; o >>= 1) r += __shfl_xor(r, o, 64);
  if (lane == 0) wsum[wave] = r;
  __syncthreads();
  float tot = 0.f;
  #pragma unroll
  for (int i = 0; i < 16; ++i) tot += wsum[i];
  float mean = tot * (1.f / 1024.f);
  int m = (ev > mean) ? 1 : 0;
  unsigned long long bal = __ballot(m);
  if (lane == 0) wcnt[wave] = __popcll(bal);
  __syncthreads();
  int wbase = 0, total = 0;
  #pragma unroll
  for (int i = 0; i < 16; ++i) {
    int c = wcnt[i];
    if (i < wave) wbase += c;
    total += c;
  }
  unsigned long long below = (lane == 63) ? ~0ULL : ((1ULL << (lane + 1)) - 1);
  int incl = __popcll(bal & below);
  int eb = wbase + incl - m;       // edges strictly before t
  int pos = m ? eb : (total + t - eb);
  order[b * NFf + pos] = t;
  msort[b * NFf + pos] = (float)m;
}

// ---------------- gather fine tokens (mask + type-embed) + LN for ALL rows
// one wave per row; coarse rows pass through tokens; fine rows gather fineb.
// emits tokens (fp32 residual stream) + ybuf (bf16 ln1 of layer 0)
__global__ __launch_bounds__(256) void k_gather_ln(float* __restrict__ tokens,
    const float* __restrict__ fineb, const int* __restrict__ order,
    const float* __restrict__ msort, const float* __restrict__ te,
    const float* __restrict__ g, const float* __restrict__ bb,
    short* __restrict__ outp) {
  int row = blockIdx.x * 4 + (threadIdx.x >> 6);
  int lane = threadIdx.x & 63;
  int b = row / NTOK, r = row % NTOK;
  float2 v;
  if (r < NCc) {
    v = ((const float2*)(tokens + (size_t)row * DD))[lane];
  } else {
    int pos = r - NCc;
    int src = order[b * NFf + pos];
    float mk = msort[b * NFf + pos];
    float2 u = ((const float2*)(fineb + (size_t)(b * NFf + src) * DD))[lane];
    float2 tv = ((const float2*)(te + DD))[lane];
    v.x = u.x * mk + tv.x;
    v.y = u.y * mk + tv.y;
    ((float2*)(tokens + (size_t)row * DD))[lane] = v;
  }
  float s = v.x + v.y;
  #pragma unroll
  for (int o = 32; o > 0; o >>= 1) s += __shfl_xor(s, o, 64);
  float mean = s * (1.f / 128.f);
  float cx = v.x - mean, cy = v.y - mean;
  float q = cx * cx + cy * cy;
  #pragma unroll
  for (int o = 32; o > 0; o >>= 1) q += __shfl_xor(q, o, 64);
  float rstd = rsqrtf(q * (1.f / 128.f) + 1e-5f);
  float2 gg = ((const float2*)g)[lane];
  float2 bv = ((const float2*)bb)[lane];
  int p = (int)(unsigned short)f2bf(cx * rstd * gg.x + bv.x)
        | ((int)(unsigned short)f2bf(cy * rstd * gg.y + bv.y) << 16);
  ((int*)(outp + (size_t)row * DD))[lane] = p;
}

// ---------------- MFMA GEMM, async DMA staging with XOR-swizzled LDS layout
__global__ __launch_bounds__(256) void k_gemm_mfma(const short* __restrict__ A,
    const short* __restrict__ Wt, const float* __restrict__ bias,
    float* __restrict__ Cf, short* __restrict__ Cb, int K, int N, int do_gelu) {
  __shared__ short Alds[64 * 128];
  __shared__ short Blds[64 * 128];
  int row0 = blockIdx.x * 64, col0 = blockIdx.y * 64;
  int t = threadIdx.x;
  int lane = t & 63, w = t >> 6;
  int m = lane & 15, quad = lane >> 4;
  int lrow = lane >> 4, jphys = lane & 15;   // staging sub-addressing
  f32x4 zero = {0.f, 0.f, 0.f, 0.f};
  f32x4 acc[4] = {zero, zero, zero, zero};

  for (int kb = 0; kb < K; kb += 128) {
    __syncthreads();
    #pragma unroll
    for (int j = 0; j < 4; ++j) {
      int c = j * 4 + w;               // chunk-group 0..15, wave-uniform
      int r = c * 4 + lrow;            // tile row this lane fetches
      int jlog = jphys ^ (r & 15);     // XOR swizzle
      __builtin_amdgcn_global_load_lds(
          (const unsigned*)&A[(size_t)(row0 + r) * K + kb + jlog * 8],
          (unsigned*)&Alds[c * 512], 16, 0, 0);
      __builtin_amdgcn_global_load_lds(
          (const unsigned*)&Wt[(size_t)(col0 + r) * K + kb + jlog * 8],
          (unsigned*)&Blds[c * 512], 16, 0, 0);
    }
    __syncthreads();
    #pragma unroll
    for (int ks = 0; ks < 4; ++ks) {   // logical chunk = quad + ks*4
      int pc = ((quad + ks * 4) ^ m) * 8;
      short8 af = *(const short8*)&Alds[(w * 16 + m) * 128 + pc];
      #pragma unroll
      for (int nt = 0; nt < 4; ++nt) {
        short8 bf = *(const short8*)&Blds[(nt * 16 + m) * 128 + pc];
        acc[nt] = __builtin_amdgcn_mfma_f32_16x16x32_bf16(af, bf, acc[nt], 0, 0, 0);
      }
    }
  }
  #pragma unroll
  for (int nt = 0; nt < 4; ++nt) {
    int col = col0 + nt * 16 + m;
    float bv = bias ? bias[col] : 0.f;
    #pragma unroll
    for (int r = 0; r < 4; ++r) {
      int row = row0 + w * 16 + quad * 4 + r;
      float v = acc[nt][r] + bv;
      if (do_gelu) v = 0.5f * v * (1.f + erff(v * 0.70710678118654752f));
      if (Cf) Cf[(size_t)row * N + col] += v;
      else    Cb[(size_t)row * N + col] = f2bf(v);
    }
  }
}

// ---------------- Wo GEMM: split-K combine A + residual + fused LN -> ybuf
// tile 32 rows x 128 cols (full row per block); grid M/32; 4 waves:
// wave w = (row-tile rt = w>>1) x (col-half ch = w&1)
__global__ __launch_bounds__(256) void k_gemm_wo_ln(const short* __restrict__ Opart,
    const float* __restrict__ Lpart, const short* __restrict__ Wt,
    const float* __restrict__ bias, float* __restrict__ tokens,
    const float* __restrict__ lng, const float* __restrict__ lnb,
    short* __restrict__ ybuf) {
  __shared__ short Alds[32 * 136];
  __shared__ short Blds[128 * 128];
  __shared__ float pls[2][32], plq[2][32];
  int row0 = blockIdx.x * 32;
  int b = row0 / NTOK;
  int rloc = row0 % NTOK;
  int qt = rloc >> 6, qoff = rloc & 63;   // 0 or 32
  int t = threadIdx.x;
  int lane = t & 63, w = t >> 6;
  int m = lane & 15, quad = lane >> 4;
  int rt = w >> 1, ch = w & 1;
  int lrow = lane >> 4, jphys = lane & 15;
  f32x4 zero = {0.f, 0.f, 0.f, 0.f};
  f32x4 acc[4] = {zero, zero, zero, zero};

  // ---- B staging (DMA, all 128 Wt rows), overlaps A combine below
  #pragma unroll
  for (int j = 0; j < 8; ++j) {
    int c = j * 4 + w;                 // 0..31 (4 rows each)
    int r = c * 4 + lrow;
    int jlog = jphys ^ (r & 15);
    __builtin_amdgcn_global_load_lds(
        (const unsigned*)&Wt[(size_t)r * 128 + jlog * 8],
        (unsigned*)&Blds[c * 512], 16, 0, 0);
  }
  // ---- A staging: combine split-K partials, normalize by L, write bf16
  #pragma unroll
  for (int it = 0; it < 2; ++it) {
    int idx = t + it * 256;            // 512 short8 chunks (32 rows x 16)
    int q = idx >> 4, j = idx & 15;
    int hh = j >> 2, dd = (j & 3) * 8;
    int qg = qoff + q;                 // q within the 64-row attention tile
    size_t pb = ((size_t)(b * HEADS + hh) * NQT + qt) * SPLIT;
    float L = Lpart[(pb + 0) * 64 + qg] + Lpart[(pb + 1) * 64 + qg]
            + Lpart[(pb + 2) * 64 + qg] + Lpart[(pb + 3) * 64 + qg];
    float o[8] = {0, 0, 0, 0, 0, 0, 0, 0};
    #pragma unroll
    for (int sk = 0; sk < SPLIT; ++sk) {
      short8 po = *(const short8*)&Opart[(pb + sk) * 2048 + qg * 32 + dd];
      #pragma unroll
      for (int i = 0; i < 8; ++i) o[i] += bf2f(po[i]);
    }
    float rs = 1.f / L;
    short8 ov;
    #pragma unroll
    for (int i = 0; i < 8; ++i) ov[i] = f2bf(o[i] * rs);
    *(short8*)&Alds[q * 136 + j * 8] = ov;
  }
  __syncthreads();
  #pragma unroll
  for (int ks = 0; ks < 4; ++ks) {
    short8 af = *(const short8*)&Alds[(rt * 16 + m) * 136 + quad * 8 + ks * 32];
    int pc = ((quad + ks * 4) ^ m) * 8;
    #pragma unroll
    for (int nt = 0; nt < 4; ++nt) {
      short8 bf = *(const short8*)&Blds[(ch * 64 + nt * 16 + m) * 128 + pc];
      acc[nt] = __builtin_amdgcn_mfma_f32_16x16x32_bf16(af, bf, acc[nt], 0, 0, 0);
    }
  }
  // ---- epilogue: residual add (write tokens) + LN across the full row
  float v[4][4];
  #pragma unroll
  for (int nt = 0; nt < 4; ++nt) {
    int col = ch * 64 + nt * 16 + m;
    float bv = bias[col];
    #pragma unroll
    for (int r = 0; r < 4; ++r) {
      int row = row0 + rt * 16 + quad * 4 + r;
      float val = acc[nt][r] + bv + tokens[(size_t)row * DD + col];
      tokens[(size_t)row * DD + col] = val;
      v[nt][r] = val;
    }
  }
  #pragma unroll
  for (int r = 0; r < 4; ++r) {
    float s = v[0][r] + v[1][r] + v[2][r] + v[3][r];
    float q = v[0][r] * v[0][r] + v[1][r] * v[1][r]
            + v[2][r] * v[2][r] + v[3][r] * v[3][r];
    #pragma unroll
    for (int o = 1; o < 16; o <<= 1) { s += __shfl_xor(s, o); q += __shfl_xor(q, o); }
    if (m == 0) {
      int lr = rt * 16 + quad * 4 + r;
      pls[ch][lr] = s;
      plq[ch][lr] = q;
    }
  }
  __syncthreads();
  #pragma unroll
  for (int r = 0; r < 4; ++r) {
    int lr = rt * 16 + quad * 4 + r;
    float S = pls[0][lr] + pls[1][lr];
    float Q = plq[0][lr] + plq[1][lr];
    float mean = S * (1.f / 128.f);
    float var = Q * (1.f / 128.f) - mean * mean;
    float rstd = rsqrtf(var + 1e-5f);
    int row = row0 + lr;
    #pragma unroll
    for (int nt = 0; nt < 4; ++nt) {
      int col = ch * 64 + nt * 16 + m;
      ybuf[(size_t)row * DD + col] = f2bf((v[nt][r] - mean) * rstd * lng[col] + lnb[col]);
    }
  }
}

// ---------------- W2 GEMM (K=256, N=128): residual + optional fused LN -> ybuf
// same 32x128 full-row tiling as k_gemm_wo_ln; A bf16 via DMA
__global__ __launch_bounds__(256) void k_gemm_w2_ln(const short* __restrict__ A,
    const short* __restrict__ Wt, const float* __restrict__ bias,
    float* __restrict__ tokens, const float* __restrict__ lng,
    const float* __restrict__ lnb, short* __restrict__ ybuf) {
  __shared__ short Alds[32 * 128];
  __shared__ short Blds[128 * 128];
  __shared__ float pls[2][32], plq[2][32];
  int row0 = blockIdx.x * 32;
  int t = threadIdx.x;
  int lane = t & 63, w = t >> 6;
  int m = lane & 15, quad = lane >> 4;
  int rt = w >> 1, ch = w & 1;
  int lrow = lane >> 4, jphys = lane & 15;
  f32x4 zero = {0.f, 0.f, 0.f, 0.f};
  f32x4 acc[4] = {zero, zero, zero, zero};

  for (int kb = 0; kb < 256; kb += 128) {
    __syncthreads();
    #pragma unroll
    for (int j = 0; j < 2; ++j) {      // A: 32 rows
      int c = j * 4 + w;               // 0..7
      int r = c * 4 + lrow;
      int jlog = jphys ^ (r & 15);
      __builtin_amdgcn_global_load_lds(
          (const unsigned*)&A[(size_t)(row0 + r) * 256 + kb + jlog * 8],
          (unsigned*)&Alds[c * 512], 16, 0, 0);
    }
    #pragma unroll
    for (int j = 0; j < 8; ++j) {      // B: 128 rows
      int c = j * 4 + w;               // 0..31
      int r = c * 4 + lrow;
      int jlog = jphys ^ (r & 15);
      __builtin_amdgcn_global_load_lds(
          (const unsigned*)&Wt[(size_t)r * 256 + kb + jlog * 8],
          (unsigned*)&Blds[c * 512], 16, 0, 0);
    }
    __syncthreads();
    #pragma unroll
    for (int ks = 0; ks < 4; ++ks) {
      int pc = ((quad + ks * 4) ^ m) * 8;
      short8 af = *(const short8*)&Alds[(rt * 16 + m) * 128 + pc];
      #pragma unroll
      for (int nt = 0; nt < 4; ++nt) {
        short8 bf = *(const short8*)&Blds[(ch * 64 + nt * 16 + m) * 128 + pc];
        acc[nt] = __builtin_amdgcn_mfma_f32_16x16x32_bf16(af, bf, acc[nt], 0, 0, 0);
      }
    }
  }
  // ---- epilogue: residual add (write tokens) + optional LN across full row
  float v[4][4];
  #pragma unroll
  for (int nt = 0; nt < 4; ++nt) {
    int col = ch * 64 + nt * 16 + m;
    float bv = bias[col];
    #pragma unroll
    for (int r = 0; r < 4; ++r) {
      int row = row0 + rt * 16 + quad * 4 + r;
      float val = acc[nt][r] + bv + tokens[(size_t)row * DD + col];
      tokens[(size_t)row * DD + col] = val;
      v[nt][r] = val;
    }
  }
  if (ybuf) {
    #pragma unroll
    for (int r = 0; r < 4; ++r) {
      float s = v[0][r] + v[1][r] + v[2][r] + v[3][r];
      float q = v[0][r] * v[0][r] + v[1][r] * v[1][r]
              + v[2][r] * v[2][r] + v[3][r] * v[3][r];
      #pragma unroll
      for (int o = 1; o < 16; o <<= 1) { s += __shfl_xor(s, o); q += __shfl_xor(q, o); }
      if (m == 0) {
        int lr = rt * 16 + quad * 4 + r;
        pls[ch][lr] = s;
        plq[ch][lr] = q;
      }
    }
    __syncthreads();
    #pragma unroll
    for (int r = 0; r < 4; ++r) {
      int lr = rt * 16 + quad * 4 + r;
      float S = pls[0][lr] + pls[1][lr];
      float Q = plq[0][lr] + plq[1][lr];
      float mean = S * (1.f / 128.f);
      float var = Q * (1.f / 128.f) - mean * mean;
      float rstd = rsqrtf(var + 1e-5f);
      int row = row0 + lr;
      #pragma unroll
      for (int nt = 0; nt < 4; ++nt) {
        int col = ch * 64 + nt * 16 + m;
        ybuf[(size_t)row * DD + col] = f2bf((v[nt][r] - mean) * rstd * lng[col] + lnb[col]);
      }
    }
  }
}

// ---------------- flash attention (R7 config): split-K, fixed-max softmax,
// swizzled Ks, two barriers/stage (implicit wave overlap does the pipelining)
__global__ __launch_bounds__(256) void k_attn4(const short* __restrict__ qkv,
    short* __restrict__ Opart, float* __restrict__ Lpart) {
  __shared__ short Ks[64 * 32];      // [key][d], DMA, chunk swizzle f(k)=(k>>1)&3
  __shared__ short Vt[32 * 74];      // [d][key], stride 74 (free scatter+gather)
  __shared__ short Pl[4][16 * 74];   // per-wave P [q][key]

  int sk = blockIdx.x % SPLIT;
  int qt = (blockIdx.x / SPLIT) % NQT;
  int h  = (blockIdx.x / (SPLIT * NQT)) % HEADS;
  int b  = blockIdx.x / (SPLIT * NQT * HEADS);
  int t = threadIdx.x;
  int lane = t & 63, w = t >> 6;
  int m = lane & 15, quad = lane >> 4;
  int q0 = qt * 64 + w * 16;

  const float scale = 0.17677669529663687f;  // 1/sqrt(32), folded into Q
  short8 qraw = *(const short8*)(qkv + ((size_t)(b * NTOK) + q0 + m) * 384 + h * HD + quad * 8);
  short8 qf;
  #pragma unroll
  for (int j = 0; j < 8; ++j) qf[j] = f2bf(bf2f(qraw[j]) * scale);

  f32x4 zero = {0.f, 0.f, 0.f, 0.f};
  f32x4 Oacc[2] = {zero, zero};
  float psum[4] = {0.f, 0.f, 0.f, 0.f};

  int skey = t >> 2, sdseg = t & 3;  // staging: key 0..63, 8 dims each
  int jlogK = sdseg ^ ((skey >> 1) & 3);
  const short* kstage = qkv + ((size_t)(b * NTOK) + skey) * 384 + 128 + h * HD + jlogK * 8;
  const short* vstage = qkv + ((size_t)(b * NTOK) + skey) * 384 + 256 + h * HD + sdseg * 8;
  int kswz = (quad ^ ((m >> 1) & 3)) * 8;   // read-side physical chunk offset

  for (int s = sk * 5; s < sk * 5 + 5; ++s) {
    __syncthreads();
    __builtin_amdgcn_global_load_lds((const unsigned*)(kstage + (size_t)s * 64 * 384),
                                     (unsigned*)&Ks[w * 512], 16, 0, 0);
    short8 vf = *(const short8*)(vstage + (size_t)s * 64 * 384);
    #pragma unroll
    for (int j = 0; j < 8; ++j) Vt[(sdseg * 8 + j) * 74 + skey] = vf[j];
    __syncthreads();

    // S = Q K^T (C-layout: row=4*quad+reg, col=m); Q pre-scaled
    f32x4 sc[4];
    #pragma unroll
    for (int ct = 0; ct < 4; ++ct) {
      short8 kfrag = *(const short8*)&Ks[(ct * 16 + m) * 32 + kswz];
      sc[ct] = __builtin_amdgcn_mfma_f32_16x16x32_bf16(qf, kfrag, zero, 0, 0, 0);
    }
    // fixed-max softmax: p = exp(s); l accumulated from TRUNCATED p (bias-free)
    #pragma unroll
    for (int ct = 0; ct < 4; ++ct)
      #pragma unroll
      for (int r = 0; r < 4; ++r) {
        float p = __expf(sc[ct][r]);
        unsigned u = __builtin_bit_cast(unsigned, p);
        psum[r] += __builtin_bit_cast(float, u & 0xffff0000u);
        Pl[w][(quad * 4 + r) * 74 + ct * 16 + m] = (short)(u >> 16);
      }
    // O += P @ V
    #pragma unroll
    for (int ks = 0; ks < 2; ++ks) {
      short8 pfrag = *(const short8*)&Pl[w][m * 74 + ks * 32 + quad * 8];
      #pragma unroll
      for (int nt = 0; nt < 2; ++nt) {
        short8 vfrag = *(const short8*)&Vt[(nt * 16 + m) * 74 + ks * 32 + quad * 8];
        Oacc[nt] = __builtin_amdgcn_mfma_f32_16x16x32_bf16(pfrag, vfrag, Oacc[nt], 0, 0, 0);
      }
    }
  }
  // single final ladder per row; write partial O (unnormalized) + l
  #pragma unroll
  for (int r = 0; r < 4; ++r) {
    float ssum = psum[r];
    #pragma unroll
    for (int o = 1; o < 16; o <<= 1) ssum += __shfl_xor(ssum, o);
    int qloc = w * 16 + quad * 4 + r;
    #pragma unroll
    for (int nt = 0; nt < 2; ++nt)
      Opart[(size_t)blockIdx.x * 2048 + qloc * 32 + nt * 16 + m] = f2bf(Oacc[nt][r]);
    if (m == 0) Lpart[(size_t)blockIdx.x * 64 + qloc] = ssum;
  }
}

// ---------------- fused decoder: coarse head + bilinear, fine head + scatter,
// conv3x3+relu+conv3x3 — one block per image, everything in LDS
__global__ __launch_bounds__(1024) void k_decoder(const float* __restrict__ tokens,
    const float* __restrict__ dWc, const float* __restrict__ dbc,
    const float* __restrict__ dWf, const float* __restrict__ dbf,
    const float* __restrict__ msort, const int* __restrict__ order,
    const float* __restrict__ fW1, const float* __restrict__ fb1,
    const float* __restrict__ fW2, const float* __restrict__ fb2,
    float* __restrict__ outp) {
  int b = blockIdx.x;
  int t = threadIdx.x;
  __shared__ float cmap[NCc];
  __shared__ float fmap[1024];
  __shared__ float cup[1024];
  __shared__ float hb[2][1024];
  {
    const float* row = tokens + (size_t)(b * NTOK + NCc + t) * DD;
    float a = 0.f;
    #pragma unroll 8
    for (int d4 = 0; d4 < 32; ++d4) {
      float4 u = ((const float4*)row)[d4];
      float4 wv = ((const float4*)dWf)[d4];
      a += u.x * wv.x + u.y * wv.y + u.z * wv.z + u.w * wv.w;
    }
    a = (a + dbf[0]) * msort[b * NFf + t];
    fmap[order[b * NFf + t]] = a;   // 32->32 AC-bilinear is identity
  }
  if (t < NCc) {
    const float* row = tokens + (size_t)(b * NTOK + t) * DD;
    float a = 0.f;
    #pragma unroll 8
    for (int d4 = 0; d4 < 32; ++d4) {
      float4 u = ((const float4*)row)[d4];
      float4 wv = ((const float4*)dWc)[d4];
      a += u.x * wv.x + u.y * wv.y + u.z * wv.z + u.w * wv.w;
    }
    cmap[t] = a + dbc[0];
  }
  __syncthreads();
  int y = t >> 5, x = t & 31;
  {
    float ys = y * (15.f / 31.f);
    float xs = x * (15.f / 31.f);
    int y0 = (int)floorf(ys); int y1 = min(y0 + 1, 15); float wy = ys - (float)y0;
    int x0 = (int)floorf(xs); int x1 = min(x0 + 1, 15); float wx = xs - (float)x0;
    cup[t] = cmap[y0 * 16 + x0] * (1.f - wy) * (1.f - wx)
           + cmap[y0 * 16 + x1] * (1.f - wy) * wx
           + cmap[y1 * 16 + x0] * wy * (1.f - wx)
           + cmap[y1 * 16 + x1] * wy * wx;
  }
  __syncthreads();
  for (int oc = 0; oc < 2; ++oc) {
    float a = fb1[oc];
    #pragma unroll
    for (int ic = 0; ic < 2; ++ic)
      #pragma unroll
      for (int ky = 0; ky < 3; ++ky)
        #pragma unroll
        for (int kx = 0; kx < 3; ++kx) {
          int yy = y + ky - 1, xx = x + kx - 1;
          float v = 0.f;
          if (yy >= 0 && yy < 32 && xx >= 0 && xx < 32)
            v = ic == 0 ? cup[yy * 32 + xx] : fmap[yy * 32 + xx];
          a += v * fW1[((oc * 2 + ic) * 3 + ky) * 3 + kx];
        }
    hb[oc][t] = fmaxf(a, 0.f);
  }
  __syncthreads();
  float a = fb2[0];
  #pragma unroll
  for (int ic = 0; ic < 2; ++ic)
    #pragma unroll
    for (int ky = 0; ky < 3; ++ky)
      #pragma unroll
      for (int kx = 0; kx < 3; ++kx) {
        int yy = y + ky - 1, xx = x + kx - 1;
        float v = (yy >= 0 && yy < 32 && xx >= 0 && xx < 32)
                      ? hb[ic][yy * 32 + xx] : 0.f;
        a += v * fW2[(ic * 3 + ky) * 3 + kx];
      }
  outp[b * 1024 + t] = a;
}

extern "C" void kernel_launch(void* const* d_in, const int* in_sizes, int n_in,
                              void* d_out, int out_size, void* d_ws, size_t ws_size,
                              hipStream_t stream) {
  const float* x    = (const float*)d_in[0];
  const float* Wpc  = (const float*)d_in[1];
  const float* bpc  = (const float*)d_in[2];
  const float* Wpf  = (const float*)d_in[3];
  const float* bpf  = (const float*)d_in[4];
  const float* te   = (const float*)d_in[5];
  const float* ln1g = (const float*)d_in[6];
  const float* ln1b = (const float*)d_in[7];
  const float* Wqkv = (const float*)d_in[8];
  const float* Wo   = (const float*)d_in[9];
  const float* bo   = (const float*)d_in[10];
  const float* ln2g = (const float*)d_in[11];
  const float* ln2b = (const float*)d_in[12];
  const float* W1   = (const float*)d_in[13];
  const float* b1   = (const float*)d_in[14];
  const float* W2   = (const float*)d_in[15];
  const float* b2   = (const float*)d_in[16];
  const float* dWc  = (const float*)d_in[17];
  const float* dbc  = (const float*)d_in[18];
  const float* dWf  = (const float*)d_in[19];
  const float* dbf  = (const float*)d_in[20];
  const float* fW1  = (const float*)d_in[21];
  const float* fb1  = (const float*)d_in[22];
  const float* fW2  = (const float*)d_in[23];
  const float* fb2  = (const float*)d_in[24];

  char* ws = (char*)d_ws;
  float* tokens = (float*)ws;                 ws += 1310720 * 4;   // fp32 [B*N,128]
  float* fineb  = (float*)ws;                 ws += 1048576 * 4;   // fp32 [B*NF,128]
  short* ybuf   = (short*)ws;                 ws += 1310720 * 2;   // bf16
  short* qkvb   = (short*)ws;                 ws += 3932160 * 2;   // bf16 [B*N,384]
  short* hbuf   = (short*)ws;                 ws += 2621440 * 2;   // bf16 [B*N,256]
  short* Opart  = (short*)ws;                 ws += (size_t)(Bx * HEADS * NQT * SPLIT) * 2048 * 2;
  float* Lpart  = (float*)ws;                 ws += (size_t)(Bx * HEADS * NQT * SPLIT) * 64 * 4;
  short* WtQKV  = (short*)ws;                 ws += 98304 * 2;     // [L][384][128]
  short* WtO    = (short*)ws;                 ws += 32768 * 2;     // [L][128][128]
  short* Wt1    = (short*)ws;                 ws += 65536 * 2;     // [L][256][128]
  short* Wt2    = (short*)ws;                 ws += 65536 * 2;     // [L][128][256]
  float* ebuf   = (float*)ws;                 ws += 8192 * 4;
  float* msort  = (float*)ws;                 ws += 8192 * 4;
  int*   order  = (int*)ws;                   ws += 8192 * 4;

  const int M = Bx * NTOK;                    // 10240

  k_prologue<<<6656, 256, 0, stream>>>(x, Wpc, bpc, Wpf, bpf, te, Wqkv, Wo, W1, W2,
                                       WtQKV, WtO, Wt1, Wt2, ebuf, tokens, fineb);
  k_edge_sort<<<Bx, 1024, 0, stream>>>(ebuf, order, msort);
  k_gather_ln<<<M / 4, 256, 0, stream>>>(tokens, fineb, order, msort, te,
                                         ln1g, ln1b, ybuf);

  for (int l = 0; l < LL; ++l) {
    k_gemm_mfma<<<dim3(M / 64, 384 / 64), 256, 0, stream>>>(
        ybuf, WtQKV + (size_t)l * 49152, nullptr, nullptr, qkvb, 128, 384, 0);
    k_attn4<<<Bx * HEADS * NQT * SPLIT, 256, 0, stream>>>(qkvb, Opart, Lpart);
    k_gemm_wo_ln<<<M / 32, 256, 0, stream>>>(
        Opart, Lpart, WtO + (size_t)l * 16384, bo + l * DD, tokens,
        ln2g + l * DD, ln2b + l * DD, ybuf);
    k_gemm_mfma<<<dim3(M / 64, 256 / 64), 256, 0, stream>>>(
        ybuf, Wt1 + (size_t)l * 32768, b1 + l * 256, nullptr, hbuf, 128, 256, 1);
    k_gemm_w2_ln<<<M / 32, 256, 0, stream>>>(
        hbuf, Wt2 + (size_t)l * 32768, b2 + l * DD, tokens,
        (l == 0) ? (ln1g + DD) : nullptr, (l == 0) ? (ln1b + DD) : nullptr,
        (l == 0) ? ybuf : nullptr);
  }

  k_decoder<<<Bx, 1024, 0, stream>>>(tokens, dWc, dbc, dWf, dbf, msort, order,
                                     fW1, fb1, fW2, fb2, (float*)d_out);
}

// Round 14
// 247.367 us; speedup vs baseline: 1.1327x; 1.0013x over previous
//
#include <hip/hip_runtime.h>
#include <math.h>

#define Bx 8
#define IMG 128
#define DD 128
#define HEADS 4
#define LL 2
#define PCc 8
#define PFf 4
#define HCc 16
#define NCc 256
#define HFf 32
#define NFf 1024
#define NTOK 1280
#define HD 32
#define SPLIT 4          // key-split factor for flash-decode attention
#define NQT 20           // NTOK/64 query tiles

typedef __attribute__((ext_vector_type(8))) short short8;
typedef __attribute__((ext_vector_type(4))) float f32x4;

__device__ __forceinline__ short f2bf(float f) {
  unsigned u = __builtin_bit_cast(unsigned, f);
  u += 0x7FFF + ((u >> 16) & 1);   // RNE
  return (short)(u >> 16);
}
__device__ __forceinline__ float bf2f(short s) {
  unsigned u = ((unsigned)(unsigned short)s) << 16;
  return __builtin_bit_cast(float, u);
}

// ---------------- batched prologue: [0,1024) prep_w, [1024,1536) sobel,
// [1536,2560) coarse embed (2 tok/block), [2560,6656) fine embed -> fineb
__global__ __launch_bounds__(256) void k_prologue(const float* __restrict__ x,
    const float* __restrict__ Wpc, const float* __restrict__ bpc,
    const float* __restrict__ Wpf, const float* __restrict__ bpf,
    const float* __restrict__ te,
    const float* __restrict__ Wqkv, const float* __restrict__ Wo,
    const float* __restrict__ W1, const float* __restrict__ W2,
    short* __restrict__ WtQKV, short* __restrict__ WtO,
    short* __restrict__ Wt1, short* __restrict__ Wt2,
    float* __restrict__ e, float* __restrict__ tokens,
    float* __restrict__ fineb) {
  int blk = blockIdx.x;
  int t = threadIdx.x;
  if (blk < 1024) {
    // ---- weight prep: transpose + bf16
    int idx = blk * 256 + t;   // 0 .. 262143
    int l = idx / 131072, r = idx % 131072;
    const float* src; short* dst; int N, off;
    if (r < 49152)      { src = Wqkv + l * 49152; dst = WtQKV + l * 49152; N = 384; off = r; }
    else if (r < 65536) { src = Wo + l * 16384;  dst = WtO + l * 16384;  N = 128; off = r - 49152; }
    else if (r < 98304) { src = W1 + l * 32768;  dst = Wt1 + l * 32768;  N = 256; off = r - 65536; }
    else                { src = W2 + l * 32768;  dst = Wt2 + l * 32768;  N = 128; off = r - 98304; }
    int k = off / N, n = off % N;
    int K = (r >= 98304) ? 256 : 128;
    dst[(size_t)n * K + k] = f2bf(src[off]);
  } else if (blk < 1536) {
    // ---- sobel + 4x4 avgpool -> cell energy
    int bt = blk - 1024;
    int b = bt >> 6, tile = bt & 63;
    int ty = tile >> 3, tx = tile & 7;
    int ly = t >> 4, lx = t & 15;
    int py = ty * 16 + ly, px = tx * 16 + lx;
    const float* img = x + (size_t)b * IMG * IMG;
    float v[3][3];
    #pragma unroll
    for (int ky = 0; ky < 3; ++ky)
      #pragma unroll
      for (int kx = 0; kx < 3; ++kx) {
        int yy = py + ky - 1, xx = px + kx - 1;
        v[ky][kx] = (yy >= 0 && yy < IMG && xx >= 0 && xx < IMG)
                        ? img[yy * IMG + xx] : 0.f;
      }
    float gx = -v[0][0] + v[0][2] - 2.f * v[1][0] + 2.f * v[1][2] - v[2][0] + v[2][2];
    float gy = -v[0][0] - 2.f * v[0][1] - v[0][2] + v[2][0] + 2.f * v[2][1] + v[2][2];
    __shared__ float sm[256];
    sm[t] = sqrtf(gx * gx + gy * gy);
    __syncthreads();
    if (t < 16) {
      int cy = t >> 2, cx = t & 3;
      float s = 0.f;
      #pragma unroll
      for (int dy = 0; dy < 4; ++dy)
        #pragma unroll
        for (int dx = 0; dx < 4; ++dx) s += sm[(cy * 4 + dy) * 16 + cx * 4 + dx];
      e[b * NFf + (ty * 4 + cy) * 32 + tx * 4 + cx] = s * (1.f / 16.f);
    }
  } else if (blk < 2560) {
    // ---- coarse patch embed, 2 tokens per block
    int bt = (blk - 1536) * 2 + (t >> 7);    // b*NC + tok
    int b = bt / NCc, tok = bt % NCc;
    int hc = tok / HCc, wc = tok % HCc;
    int half = t >> 7, d = t & 127;
    __shared__ float patch[2][PCc * PCc];
    if (d < PCc * PCc) {
      int pi = d / PCc, pj = d % PCc;
      patch[half][d] = x[(b * IMG + hc * PCc + pi) * IMG + wc * PCc + pj];
    }
    __syncthreads();
    float acc = bpc[d] + te[d];
    #pragma unroll 8
    for (int i = 0; i < PCc * PCc; ++i) acc += patch[half][i] * Wpc[i * DD + d];
    tokens[(size_t)(b * NTOK + tok) * DD + d] = acc;
  } else {
    // ---- fine patch embed, 2 tokens per block -> fineb (unsorted, unmasked)
    int ft = (blk - 2560) * 2 + (t >> 7);    // global fine token 0..8191
    int b = ft >> 10, tloc = ft & 1023;
    int hf = tloc >> 5, wf = tloc & 31;
    int half = t >> 7, d = t & 127;
    __shared__ float patch[2][PFf * PFf];
    if (d < PFf * PFf) {
      int pi = d / PFf, pj = d % PFf;
      patch[half][d] = x[(b * IMG + hf * PFf + pi) * IMG + wf * PFf + pj];
    }
    __syncthreads();
    float acc = bpf[d];
    #pragma unroll
    for (int i = 0; i < PFf * PFf; ++i) acc += patch[half][i] * Wpf[i * DD + d];
    fineb[(size_t)(b * NFf + tloc) * DD + d] = acc;
  }
}

// ---------------- mask at per-image mean -> stable-sort order via ballot scan
__global__ __launch_bounds__(1024) void k_edge_sort(const float* __restrict__ e,
    int* __restrict__ order, float* __restrict__ msort) {
  int b = blockIdx.x;
  int t = threadIdx.x;
  int lane = t & 63, wave = t >> 6;
  float ev = e[b * NFf + t];
  __shared__ float wsum[16];
  __shared__ int wcnt[16];
  float r = ev;
  #pragma unroll
  for (int o = 32; o > 0; o >>= 1) r += __shfl_xor(r, o, 64);
  if (lane == 0) wsum[wave] = r;
  __syncthreads();
  float tot = 0.f;
  #pragma unroll
  for (int i = 0; i < 16; ++i) tot += wsum[i];
  float mean = tot * (1.f / 1024.f);
  int m = (ev > mean) ? 1 : 0;
  unsigned long long bal = __ballot(m);
  if (lane == 0) wcnt[wave] = __popcll(bal);
  __syncthreads();
  int wbase = 0, total = 0;
  #pragma unroll
  for (int i = 0; i < 16; ++i) {
    int c = wcnt[i];
    if (i < wave) wbase += c;
    total += c;
  }
  unsigned long long below = (lane == 63) ? ~0ULL : ((1ULL << (lane + 1)) - 1);
  int incl = __popcll(bal & below);
  int eb = wbase + incl - m;       // edges strictly before t
  int pos = m ? eb : (total + t - eb);
  order[b * NFf + pos] = t;
  msort[b * NFf + pos] = (float)m;
}

// ---------------- gather fine tokens (mask + type-embed) + LN for ALL rows
__global__ __launch_bounds__(256) void k_gather_ln(float* __restrict__ tokens,
    const float* __restrict__ fineb, const int* __restrict__ order,
    const float* __restrict__ msort, const float* __restrict__ te,
    const float* __restrict__ g, const float* __restrict__ bb,
    short* __restrict__ outp) {
  int row = blockIdx.x * 4 + (threadIdx.x >> 6);
  int lane = threadIdx.x & 63;
  int b = row / NTOK, r = row % NTOK;
  float2 v;
  if (r < NCc) {
    v = ((const float2*)(tokens + (size_t)row * DD))[lane];
  } else {
    int pos = r - NCc;
    int src = order[b * NFf + pos];
    float mk = msort[b * NFf + pos];
    float2 u = ((const float2*)(fineb + (size_t)(b * NFf + src) * DD))[lane];
    float2 tv = ((const float2*)(te + DD))[lane];
    v.x = u.x * mk + tv.x;
    v.y = u.y * mk + tv.y;
    ((float2*)(tokens + (size_t)row * DD))[lane] = v;
  }
  float s = v.x + v.y;
  #pragma unroll
  for (int o = 32; o > 0; o >>= 1) s += __shfl_xor(s, o, 64);
  float mean = s * (1.f / 128.f);
  float cx = v.x - mean, cy = v.y - mean;
  float q = cx * cx + cy * cy;
  #pragma unroll
  for (int o = 32; o > 0; o >>= 1) q += __shfl_xor(q, o, 64);
  float rstd = rsqrtf(q * (1.f / 128.f) + 1e-5f);
  float2 gg = ((const float2*)g)[lane];
  float2 bv = ((const float2*)bb)[lane];
  int p = (int)(unsigned short)f2bf(cx * rstd * gg.x + bv.x)
        | ((int)(unsigned short)f2bf(cy * rstd * gg.y + bv.y) << 16);
  ((int*)(outp + (size_t)row * DD))[lane] = p;
}

// ---------------- MFMA GEMM, async DMA staging with XOR-swizzled LDS layout
__global__ __launch_bounds__(256) void k_gemm_mfma(const short* __restrict__ A,
    const short* __restrict__ Wt, const float* __restrict__ bias,
    float* __restrict__ Cf, short* __restrict__ Cb, int K, int N, int do_gelu) {
  __shared__ short Alds[64 * 128];
  __shared__ short Blds[64 * 128];
  int row0 = blockIdx.x * 64, col0 = blockIdx.y * 64;
  int t = threadIdx.x;
  int lane = t & 63, w = t >> 6;
  int m = lane & 15, quad = lane >> 4;
  int lrow = lane >> 4, jphys = lane & 15;   // staging sub-addressing
  f32x4 zero = {0.f, 0.f, 0.f, 0.f};
  f32x4 acc[4] = {zero, zero, zero, zero};

  for (int kb = 0; kb < K; kb += 128) {
    __syncthreads();
    #pragma unroll
    for (int j = 0; j < 4; ++j) {
      int c = j * 4 + w;               // chunk-group 0..15, wave-uniform
      int r = c * 4 + lrow;            // tile row this lane fetches
      int jlog = jphys ^ (r & 15);     // XOR swizzle
      __builtin_amdgcn_global_load_lds(
          (const unsigned*)&A[(size_t)(row0 + r) * K + kb + jlog * 8],
          (unsigned*)&Alds[c * 512], 16, 0, 0);
      __builtin_amdgcn_global_load_lds(
          (const unsigned*)&Wt[(size_t)(col0 + r) * K + kb + jlog * 8],
          (unsigned*)&Blds[c * 512], 16, 0, 0);
    }
    __syncthreads();
    #pragma unroll
    for (int ks = 0; ks < 4; ++ks) {   // logical chunk = quad + ks*4
      int pc = ((quad + ks * 4) ^ m) * 8;
      short8 af = *(const short8*)&Alds[(w * 16 + m) * 128 + pc];
      #pragma unroll
      for (int nt = 0; nt < 4; ++nt) {
        short8 bf = *(const short8*)&Blds[(nt * 16 + m) * 128 + pc];
        acc[nt] = __builtin_amdgcn_mfma_f32_16x16x32_bf16(af, bf, acc[nt], 0, 0, 0);
      }
    }
  }
  #pragma unroll
  for (int nt = 0; nt < 4; ++nt) {
    int col = col0 + nt * 16 + m;
    float bv = bias ? bias[col] : 0.f;
    #pragma unroll
    for (int r = 0; r < 4; ++r) {
      int row = row0 + w * 16 + quad * 4 + r;
      float v = acc[nt][r] + bv;
      if (do_gelu) v = 0.5f * v * (1.f + erff(v * 0.70710678118654752f));
      if (Cf) Cf[(size_t)row * N + col] += v;
      else    Cb[(size_t)row * N + col] = f2bf(v);
    }
  }
}

// ---------------- Wo GEMM: split-K combine A + residual + fused LN -> ybuf
// tile 32 rows x 128 cols (full row per block); grid M/32; 4 waves:
// wave w = (row-tile rt = w>>1) x (col-half ch = w&1)
__global__ __launch_bounds__(256) void k_gemm_wo_ln(const short* __restrict__ Opart,
    const float* __restrict__ Lpart, const short* __restrict__ Wt,
    const float* __restrict__ bias, float* __restrict__ tokens,
    const float* __restrict__ lng, const float* __restrict__ lnb,
    short* __restrict__ ybuf) {
  __shared__ short Alds[32 * 136];
  __shared__ short Blds[128 * 128];
  __shared__ float pls[2][32], plq[2][32];
  int row0 = blockIdx.x * 32;
  int b = row0 / NTOK;
  int rloc = row0 % NTOK;
  int qt = rloc >> 6, qoff = rloc & 63;   // 0 or 32
  int t = threadIdx.x;
  int lane = t & 63, w = t >> 6;
  int m = lane & 15, quad = lane >> 4;
  int rt = w >> 1, ch = w & 1;
  int lrow = lane >> 4, jphys = lane & 15;
  f32x4 zero = {0.f, 0.f, 0.f, 0.f};
  f32x4 acc[4] = {zero, zero, zero, zero};

  // ---- B staging (DMA, all 128 Wt rows), overlaps A combine below
  #pragma unroll
  for (int j = 0; j < 8; ++j) {
    int c = j * 4 + w;                 // 0..31 (4 rows each)
    int r = c * 4 + lrow;
    int jlog = jphys ^ (r & 15);
    __builtin_amdgcn_global_load_lds(
        (const unsigned*)&Wt[(size_t)r * 128 + jlog * 8],
        (unsigned*)&Blds[c * 512], 16, 0, 0);
  }
  // ---- A staging: combine split-K partials, normalize by L, write bf16
  #pragma unroll
  for (int it = 0; it < 2; ++it) {
    int idx = t + it * 256;            // 512 short8 chunks (32 rows x 16)
    int q = idx >> 4, j = idx & 15;
    int hh = j >> 2, dd = (j & 3) * 8;
    int qg = qoff + q;                 // q within the 64-row attention tile
    size_t pb = ((size_t)(b * HEADS + hh) * NQT + qt) * SPLIT;
    float L = Lpart[(pb + 0) * 64 + qg] + Lpart[(pb + 1) * 64 + qg]
            + Lpart[(pb + 2) * 64 + qg] + Lpart[(pb + 3) * 64 + qg];
    float o[8] = {0, 0, 0, 0, 0, 0, 0, 0};
    #pragma unroll
    for (int sk = 0; sk < SPLIT; ++sk) {
      short8 po = *(const short8*)&Opart[(pb + sk) * 2048 + qg * 32 + dd];
      #pragma unroll
      for (int i = 0; i < 8; ++i) o[i] += bf2f(po[i]);
    }
    float rs = 1.f / L;
    short8 ov;
    #pragma unroll
    for (int i = 0; i < 8; ++i) ov[i] = f2bf(o[i] * rs);
    *(short8*)&Alds[q * 136 + j * 8] = ov;
  }
  __syncthreads();
  #pragma unroll
  for (int ks = 0; ks < 4; ++ks) {
    short8 af = *(const short8*)&Alds[(rt * 16 + m) * 136 + quad * 8 + ks * 32];
    int pc = ((quad + ks * 4) ^ m) * 8;
    #pragma unroll
    for (int nt = 0; nt < 4; ++nt) {
      short8 bf = *(const short8*)&Blds[(ch * 64 + nt * 16 + m) * 128 + pc];
      acc[nt] = __builtin_amdgcn_mfma_f32_16x16x32_bf16(af, bf, acc[nt], 0, 0, 0);
    }
  }
  // ---- epilogue: residual add (write tokens) + LN across the full row
  float v[4][4];
  #pragma unroll
  for (int nt = 0; nt < 4; ++nt) {
    int col = ch * 64 + nt * 16 + m;
    float bv = bias[col];
    #pragma unroll
    for (int r = 0; r < 4; ++r) {
      int row = row0 + rt * 16 + quad * 4 + r;
      float val = acc[nt][r] + bv + tokens[(size_t)row * DD + col];
      tokens[(size_t)row * DD + col] = val;
      v[nt][r] = val;
    }
  }
  #pragma unroll
  for (int r = 0; r < 4; ++r) {
    float s = v[0][r] + v[1][r] + v[2][r] + v[3][r];
    float q = v[0][r] * v[0][r] + v[1][r] * v[1][r]
            + v[2][r] * v[2][r] + v[3][r] * v[3][r];
    #pragma unroll
    for (int o = 1; o < 16; o <<= 1) { s += __shfl_xor(s, o); q += __shfl_xor(q, o); }
    if (m == 0) {
      int lr = rt * 16 + quad * 4 + r;
      pls[ch][lr] = s;
      plq[ch][lr] = q;
    }
  }
  __syncthreads();
  #pragma unroll
  for (int r = 0; r < 4; ++r) {
    int lr = rt * 16 + quad * 4 + r;
    float S = pls[0][lr] + pls[1][lr];
    float Q = plq[0][lr] + plq[1][lr];
    float mean = S * (1.f / 128.f);
    float var = Q * (1.f / 128.f) - mean * mean;
    float rstd = rsqrtf(var + 1e-5f);
    int row = row0 + lr;
    #pragma unroll
    for (int nt = 0; nt < 4; ++nt) {
      int col = ch * 64 + nt * 16 + m;
      ybuf[(size_t)row * DD + col] = f2bf((v[nt][r] - mean) * rstd * lng[col] + lnb[col]);
    }
  }
}

// ---------------- fused MLP: h = gelu(ybuf@W1 + b1) in LDS, then
// tokens += h@W2 + b2, optional LN -> ybuf. 32 rows x full width per block.
// Removes the hbuf global round-trip (producer-side fusion, zero redundancy).
__global__ __launch_bounds__(256) void k_gemm_mlp(const short* __restrict__ A,
    const short* __restrict__ Wt1, const float* __restrict__ b1,
    const short* __restrict__ Wt2, const float* __restrict__ b2,
    float* __restrict__ tokens, const float* __restrict__ lng,
    const float* __restrict__ lnb, short* __restrict__ ybuf) {
  __shared__ short Alds[32 * 128];
  __shared__ short Blds[128 * 128];
  __shared__ short Hlds[32 * 268];   // pad 268: A-reads ~2-way, writes spread
  __shared__ float pls[2][32], plq[2][32];
  int row0 = blockIdx.x * 32;
  int t = threadIdx.x;
  int lane = t & 63, w = t >> 6;
  int m = lane & 15, quad = lane >> 4;
  int rt = w >> 1, ch = w & 1;
  int lrow = lane >> 4, jphys = lane & 15;
  f32x4 zero = {0.f, 0.f, 0.f, 0.f};

  // ---- stage A (32 ybuf rows), swizzled
  #pragma unroll
  for (int j = 0; j < 2; ++j) {
    int c = j * 4 + w;
    int r = c * 4 + lrow;
    int jlog = jphys ^ (r & 15);
    __builtin_amdgcn_global_load_lds(
        (const unsigned*)&A[(size_t)(row0 + r) * 128 + jlog * 8],
        (unsigned*)&Alds[c * 512], 16, 0, 0);
  }
  // ---- W1 in two 128-col halves; gelu -> Hlds bf16
  for (int hh = 0; hh < 2; ++hh) {
    #pragma unroll
    for (int j = 0; j < 8; ++j) {
      int c = j * 4 + w;
      int r = c * 4 + lrow;
      int jlog = jphys ^ (r & 15);
      __builtin_amdgcn_global_load_lds(
          (const unsigned*)&Wt1[(size_t)(hh * 128 + r) * 128 + jlog * 8],
          (unsigned*)&Blds[c * 512], 16, 0, 0);
    }
    __syncthreads();
    f32x4 acc[4] = {zero, zero, zero, zero};
    #pragma unroll
    for (int ks = 0; ks < 4; ++ks) {
      int pc = ((quad + ks * 4) ^ m) * 8;
      short8 af = *(const short8*)&Alds[(rt * 16 + m) * 128 + pc];
      #pragma unroll
      for (int nt = 0; nt < 4; ++nt) {
        short8 bf = *(const short8*)&Blds[(ch * 64 + nt * 16 + m) * 128 + pc];
        acc[nt] = __builtin_amdgcn_mfma_f32_16x16x32_bf16(af, bf, acc[nt], 0, 0, 0);
      }
    }
    #pragma unroll
    for (int nt = 0; nt < 4; ++nt) {
      int n = hh * 128 + ch * 64 + nt * 16 + m;
      float bv = b1[n];
      #pragma unroll
      for (int r = 0; r < 4; ++r) {
        float v = acc[nt][r] + bv;
        v = 0.5f * v * (1.f + erff(v * 0.70710678118654752f));
        Hlds[(rt * 16 + quad * 4 + r) * 268 + n] = f2bf(v);
      }
    }
    __syncthreads();   // Blds reuse guard + Hlds publish
  }
  // ---- W2: K=256 in two chunks (chunk kb == Hlds half kb)
  f32x4 acc[4] = {zero, zero, zero, zero};
  for (int kb = 0; kb < 2; ++kb) {
    if (kb) __syncthreads();           // Blds reuse guard
    #pragma unroll
    for (int j = 0; j < 8; ++j) {
      int c = j * 4 + w;
      int r = c * 4 + lrow;
      int jlog = jphys ^ (r & 15);
      __builtin_amdgcn_global_load_lds(
          (const unsigned*)&Wt2[(size_t)r * 256 + kb * 128 + jlog * 8],
          (unsigned*)&Blds[c * 512], 16, 0, 0);
    }
    __syncthreads();
    #pragma unroll
    for (int ks = 0; ks < 4; ++ks) {
      int pc = ((quad + ks * 4) ^ m) * 8;   // B logical chunk = quad+ks*4
      short8 af = *(const short8*)&Hlds[(rt * 16 + m) * 268 + kb * 128
                                        + quad * 8 + ks * 32];  // same logical k
      #pragma unroll
      for (int nt = 0; nt < 4; ++nt) {
        short8 bf = *(const short8*)&Blds[(ch * 64 + nt * 16 + m) * 128 + pc];
        acc[nt] = __builtin_amdgcn_mfma_f32_16x16x32_bf16(af, bf, acc[nt], 0, 0, 0);
      }
    }
  }
  // ---- epilogue: residual add (write tokens) + optional LN -> ybuf
  float v[4][4];
  #pragma unroll
  for (int nt = 0; nt < 4; ++nt) {
    int col = ch * 64 + nt * 16 + m;
    float bv = b2[col];
    #pragma unroll
    for (int r = 0; r < 4; ++r) {
      int row = row0 + rt * 16 + quad * 4 + r;
      float val = acc[nt][r] + bv + tokens[(size_t)row * DD + col];
      tokens[(size_t)row * DD + col] = val;
      v[nt][r] = val;
    }
  }
  if (ybuf) {
    #pragma unroll
    for (int r = 0; r < 4; ++r) {
      float s = v[0][r] + v[1][r] + v[2][r] + v[3][r];
      float q = v[0][r] * v[0][r] + v[1][r] * v[1][r]
              + v[2][r] * v[2][r] + v[3][r] * v[3][r];
      #pragma unroll
      for (int o = 1; o < 16; o <<= 1) { s += __shfl_xor(s, o); q += __shfl_xor(q, o); }
      if (m == 0) {
        int lr = rt * 16 + quad * 4 + r;
        pls[ch][lr] = s;
        plq[ch][lr] = q;
      }
    }
    __syncthreads();
    #pragma unroll
    for (int r = 0; r < 4; ++r) {
      int lr = rt * 16 + quad * 4 + r;
      float S = pls[0][lr] + pls[1][lr];
      float Q = plq[0][lr] + plq[1][lr];
      float mean = S * (1.f / 128.f);
      float var = Q * (1.f / 128.f) - mean * mean;
      float rstd = rsqrtf(var + 1e-5f);
      int row = row0 + lr;
      #pragma unroll
      for (int nt = 0; nt < 4; ++nt) {
        int col = ch * 64 + nt * 16 + m;
        ybuf[(size_t)row * DD + col] = f2bf((v[nt][r] - mean) * rstd * lng[col] + lnb[col]);
      }
    }
  }
}

// ---------------- flash attention (R7 config): split-K, fixed-max softmax,
// swizzled Ks, two barriers/stage (implicit wave overlap does the pipelining)
__global__ __launch_bounds__(256) void k_attn4(const short* __restrict__ qkv,
    short* __restrict__ Opart, float* __restrict__ Lpart) {
  __shared__ short Ks[64 * 32];      // [key][d], DMA, chunk swizzle f(k)=(k>>1)&3
  __shared__ short Vt[32 * 74];      // [d][key], stride 74 (free scatter+gather)
  __shared__ short Pl[4][16 * 74];   // per-wave P [q][key]

  int sk = blockIdx.x % SPLIT;
  int qt = (blockIdx.x / SPLIT) % NQT;
  int h  = (blockIdx.x / (SPLIT * NQT)) % HEADS;
  int b  = blockIdx.x / (SPLIT * NQT * HEADS);
  int t = threadIdx.x;
  int lane = t & 63, w = t >> 6;
  int m = lane & 15, quad = lane >> 4;
  int q0 = qt * 64 + w * 16;

  const float scale = 0.17677669529663687f;  // 1/sqrt(32), folded into Q
  short8 qraw = *(const short8*)(qkv + ((size_t)(b * NTOK) + q0 + m) * 384 + h * HD + quad * 8);
  short8 qf;
  #pragma unroll
  for (int j = 0; j < 8; ++j) qf[j] = f2bf(bf2f(qraw[j]) * scale);

  f32x4 zero = {0.f, 0.f, 0.f, 0.f};
  f32x4 Oacc[2] = {zero, zero};
  float psum[4] = {0.f, 0.f, 0.f, 0.f};

  int skey = t >> 2, sdseg = t & 3;  // staging: key 0..63, 8 dims each
  int jlogK = sdseg ^ ((skey >> 1) & 3);
  const short* kstage = qkv + ((size_t)(b * NTOK) + skey) * 384 + 128 + h * HD + jlogK * 8;
  const short* vstage = qkv + ((size_t)(b * NTOK) + skey) * 384 + 256 + h * HD + sdseg * 8;
  int kswz = (quad ^ ((m >> 1) & 3)) * 8;   // read-side physical chunk offset

  for (int s = sk * 5; s < sk * 5 + 5; ++s) {
    __syncthreads();
    __builtin_amdgcn_global_load_lds((const unsigned*)(kstage + (size_t)s * 64 * 384),
                                     (unsigned*)&Ks[w * 512], 16, 0, 0);
    short8 vf = *(const short8*)(vstage + (size_t)s * 64 * 384);
    #pragma unroll
    for (int j = 0; j < 8; ++j) Vt[(sdseg * 8 + j) * 74 + skey] = vf[j];
    __syncthreads();

    // S = Q K^T (C-layout: row=4*quad+reg, col=m); Q pre-scaled
    f32x4 sc[4];
    #pragma unroll
    for (int ct = 0; ct < 4; ++ct) {
      short8 kfrag = *(const short8*)&Ks[(ct * 16 + m) * 32 + kswz];
      sc[ct] = __builtin_amdgcn_mfma_f32_16x16x32_bf16(qf, kfrag, zero, 0, 0, 0);
    }
    // fixed-max softmax: p = exp(s); l accumulated from TRUNCATED p (bias-free)
    #pragma unroll
    for (int ct = 0; ct < 4; ++ct)
      #pragma unroll
      for (int r = 0; r < 4; ++r) {
        float p = __expf(sc[ct][r]);
        unsigned u = __builtin_bit_cast(unsigned, p);
        psum[r] += __builtin_bit_cast(float, u & 0xffff0000u);
        Pl[w][(quad * 4 + r) * 74 + ct * 16 + m] = (short)(u >> 16);
      }
    // O += P @ V
    #pragma unroll
    for (int ks = 0; ks < 2; ++ks) {
      short8 pfrag = *(const short8*)&Pl[w][m * 74 + ks * 32 + quad * 8];
      #pragma unroll
      for (int nt = 0; nt < 2; ++nt) {
        short8 vfrag = *(const short8*)&Vt[(nt * 16 + m) * 74 + ks * 32 + quad * 8];
        Oacc[nt] = __builtin_amdgcn_mfma_f32_16x16x32_bf16(pfrag, vfrag, Oacc[nt], 0, 0, 0);
      }
    }
  }
  // single final ladder per row; write partial O (unnormalized) + l
  #pragma unroll
  for (int r = 0; r < 4; ++r) {
    float ssum = psum[r];
    #pragma unroll
    for (int o = 1; o < 16; o <<= 1) ssum += __shfl_xor(ssum, o);
    int qloc = w * 16 + quad * 4 + r;
    #pragma unroll
    for (int nt = 0; nt < 2; ++nt)
      Opart[(size_t)blockIdx.x * 2048 + qloc * 32 + nt * 16 + m] = f2bf(Oacc[nt][r]);
    if (m == 0) Lpart[(size_t)blockIdx.x * 64 + qloc] = ssum;
  }
}

// ---------------- fused decoder: coarse head + bilinear, fine head + scatter,
// conv3x3+relu+conv3x3 — one block per image, everything in LDS
__global__ __launch_bounds__(1024) void k_decoder(const float* __restrict__ tokens,
    const float* __restrict__ dWc, const float* __restrict__ dbc,
    const float* __restrict__ dWf, const float* __restrict__ dbf,
    const float* __restrict__ msort, const int* __restrict__ order,
    const float* __restrict__ fW1, const float* __restrict__ fb1,
    const float* __restrict__ fW2, const float* __restrict__ fb2,
    float* __restrict__ outp) {
  int b = blockIdx.x;
  int t = threadIdx.x;
  __shared__ float cmap[NCc];
  __shared__ float fmap[1024];
  __shared__ float cup[1024];
  __shared__ float hb[2][1024];
  {
    const float* row = tokens + (size_t)(b * NTOK + NCc + t) * DD;
    float a = 0.f;
    #pragma unroll 8
    for (int d4 = 0; d4 < 32; ++d4) {
      float4 u = ((const float4*)row)[d4];
      float4 wv = ((const float4*)dWf)[d4];
      a += u.x * wv.x + u.y * wv.y + u.z * wv.z + u.w * wv.w;
    }
    a = (a + dbf[0]) * msort[b * NFf + t];
    fmap[order[b * NFf + t]] = a;   // 32->32 AC-bilinear is identity
  }
  if (t < NCc) {
    const float* row = tokens + (size_t)(b * NTOK + t) * DD;
    float a = 0.f;
    #pragma unroll 8
    for (int d4 = 0; d4 < 32; ++d4) {
      float4 u = ((const float4*)row)[d4];
      float4 wv = ((const float4*)dWc)[d4];
      a += u.x * wv.x + u.y * wv.y + u.z * wv.z + u.w * wv.w;
    }
    cmap[t] = a + dbc[0];
  }
  __syncthreads();
  int y = t >> 5, x = t & 31;
  {
    float ys = y * (15.f / 31.f);
    float xs = x * (15.f / 31.f);
    int y0 = (int)floorf(ys); int y1 = min(y0 + 1, 15); float wy = ys - (float)y0;
    int x0 = (int)floorf(xs); int x1 = min(x0 + 1, 15); float wx = xs - (float)x0;
    cup[t] = cmap[y0 * 16 + x0] * (1.f - wy) * (1.f - wx)
           + cmap[y0 * 16 + x1] * (1.f - wy) * wx
           + cmap[y1 * 16 + x0] * wy * (1.f - wx)
           + cmap[y1 * 16 + x1] * wy * wx;
  }
  __syncthreads();
  for (int oc = 0; oc < 2; ++oc) {
    float a = fb1[oc];
    #pragma unroll
    for (int ic = 0; ic < 2; ++ic)
      #pragma unroll
      for (int ky = 0; ky < 3; ++ky)
        #pragma unroll
        for (int kx = 0; kx < 3; ++kx) {
          int yy = y + ky - 1, xx = x + kx - 1;
          float v = 0.f;
          if (yy >= 0 && yy < 32 && xx >= 0 && xx < 32)
            v = ic == 0 ? cup[yy * 32 + xx] : fmap[yy * 32 + xx];
          a += v * fW1[((oc * 2 + ic) * 3 + ky) * 3 + kx];
        }
    hb[oc][t] = fmaxf(a, 0.f);
  }
  __syncthreads();
  float a = fb2[0];
  #pragma unroll
  for (int ic = 0; ic < 2; ++ic)
    #pragma unroll
    for (int ky = 0; ky < 3; ++ky)
      #pragma unroll
      for (int kx = 0; kx < 3; ++kx) {
        int yy = y + ky - 1, xx = x + kx - 1;
        float v = (yy >= 0 && yy < 32 && xx >= 0 && xx < 32)
                      ? hb[ic][yy * 32 + xx] : 0.f;
        a += v * fW2[(ic * 3 + ky) * 3 + kx];
      }
  outp[b * 1024 + t] = a;
}

extern "C" void kernel_launch(void* const* d_in, const int* in_sizes, int n_in,
                              void* d_out, int out_size, void* d_ws, size_t ws_size,
                              hipStream_t stream) {
  const float* x    = (const float*)d_in[0];
  const float* Wpc  = (const float*)d_in[1];
  const float* bpc  = (const float*)d_in[2];
  const float* Wpf  = (const float*)d_in[3];
  const float* bpf  = (const float*)d_in[4];
  const float* te   = (const float*)d_in[5];
  const float* ln1g = (const float*)d_in[6];
  const float* ln1b = (const float*)d_in[7];
  const float* Wqkv = (const float*)d_in[8];
  const float* Wo   = (const float*)d_in[9];
  const float* bo   = (const float*)d_in[10];
  const float* ln2g = (const float*)d_in[11];
  const float* ln2b = (const float*)d_in[12];
  const float* W1   = (const float*)d_in[13];
  const float* b1   = (const float*)d_in[14];
  const float* W2   = (const float*)d_in[15];
  const float* b2   = (const float*)d_in[16];
  const float* dWc  = (const float*)d_in[17];
  const float* dbc  = (const float*)d_in[18];
  const float* dWf  = (const float*)d_in[19];
  const float* dbf  = (const float*)d_in[20];
  const float* fW1  = (const float*)d_in[21];
  const float* fb1  = (const float*)d_in[22];
  const float* fW2  = (const float*)d_in[23];
  const float* fb2  = (const float*)d_in[24];

  char* ws = (char*)d_ws;
  float* tokens = (float*)ws;                 ws += 1310720 * 4;   // fp32 [B*N,128]
  float* fineb  = (float*)ws;                 ws += 1048576 * 4;   // fp32 [B*NF,128]
  short* ybuf   = (short*)ws;                 ws += 1310720 * 2;   // bf16
  short* qkvb   = (short*)ws;                 ws += 3932160 * 2;   // bf16 [B*N,384]
  short* Opart  = (short*)ws;                 ws += (size_t)(Bx * HEADS * NQT * SPLIT) * 2048 * 2;
  float* Lpart  = (float*)ws;                 ws += (size_t)(Bx * HEADS * NQT * SPLIT) * 64 * 4;
  short* WtQKV  = (short*)ws;                 ws += 98304 * 2;     // [L][384][128]
  short* WtO    = (short*)ws;                 ws += 32768 * 2;     // [L][128][128]
  short* Wt1    = (short*)ws;                 ws += 65536 * 2;     // [L][256][128]
  short* Wt2    = (short*)ws;                 ws += 65536 * 2;     // [L][128][256]
  float* ebuf   = (float*)ws;                 ws += 8192 * 4;
  float* msort  = (float*)ws;                 ws += 8192 * 4;
  int*   order  = (int*)ws;                   ws += 8192 * 4;

  const int M = Bx * NTOK;                    // 10240

  k_prologue<<<6656, 256, 0, stream>>>(x, Wpc, bpc, Wpf, bpf, te, Wqkv, Wo, W1, W2,
                                       WtQKV, WtO, Wt1, Wt2, ebuf, tokens, fineb);
  k_edge_sort<<<Bx, 1024, 0, stream>>>(ebuf, order, msort);
  k_gather_ln<<<M / 4, 256, 0, stream>>>(tokens, fineb, order, msort, te,
                                         ln1g, ln1b, ybuf);

  for (int l = 0; l < LL; ++l) {
    k_gemm_mfma<<<dim3(M / 64, 384 / 64), 256, 0, stream>>>(
        ybuf, WtQKV + (size_t)l * 49152, nullptr, nullptr, qkvb, 128, 384, 0);
    k_attn4<<<Bx * HEADS * NQT * SPLIT, 256, 0, stream>>>(qkvb, Opart, Lpart);
    k_gemm_wo_ln<<<M / 32, 256, 0, stream>>>(
        Opart, Lpart, WtO + (size_t)l * 16384, bo + l * DD, tokens,
        ln2g + l * DD, ln2b + l * DD, ybuf);
    k_gemm_mlp<<<M / 32, 256, 0, stream>>>(
        ybuf, Wt1 + (size_t)l * 32768, b1 + l * 256,
        Wt2 + (size_t)l * 32768, b2 + l * DD, tokens,
        (l == 0) ? (ln1g + DD) : nullptr, (l == 0) ? (ln1b + DD) : nullptr,
        (l == 0) ? ybuf : nullptr);
  }

  k_decoder<<<Bx, 1024, 0, stream>>>(tokens, dWc, dbc, dWf, dbf, msort, order,
                                     fW1, fb1, fW2, fb2, (float*)d_out);
}